// Round 12
// baseline (6192.707 us; speedup 1.0000x reference)
//
#include <hip/hip_runtime.h>
#include <stdint.h>

// ---------------------------------------------------------------------------
// RNN rollout. Phase 1: teacher-forced recurrence (scalar, 4-way ILP, R19) +
// bulk psi (64-row blocks, R17). Phase 2: persistent AR kernel, 8 groups x
// 32 members, member m -> XCD m%8 (weight slices L2-resident, R6/R8).
// Failed variants (do not retry): co-located groups (R9), in-grid psi
// fusion (R11), redundant full-L1 (R12), epoch-flag exchange (R13),
// MALL-atomic L5 reduction (R15), chunked per-layer psi GEMMs (R16),
// MFMA teacher-forced recurrence (R18: 16 waves on 256 CUs).
// R20 change (AR sync structure only): SPLIT-PUBLISH. Each wave publishes
// its OWN 16-col half of the slice (wave w -> granules {2w,2w+1}, 32 x 16B
// stores in parallel) -> the cross-wave hsl dependency disappears -> the
// pre-publish __syncthreads is DELETED (3 -> 2 barriers/hop). Both waves
// drain + both lane0s arrive (barrier target 64/group/hop). Bytes written
// and reader side byte-identical to R14; only lane->granule mapping moved.
// Sizes fixed: B=128, T=256, HOR=512, OBS=32, LAT=256, HID=1024.
// ---------------------------------------------------------------------------

#define BATCH 128
#define TTF   256
#define HOR   512
#define OBS   32
#define LAT   256
#define HID   1024

#define GROUPS  8
#define MEMBERS 32
#define ARBLOCKS (GROUPS * MEMBERS)
#define ARTHREADS 128

typedef __attribute__((ext_vector_type(8))) short short8;
typedef __attribute__((ext_vector_type(4))) float floatx4;

// ---- workspace layout (bytes) ----
#define OFF_WB1   ((size_t)0)                          // 1024x256 bf16 ([col][k])
#define OFF_WB2   (OFF_WB1 + (size_t)HID*LAT*2)        // 1024x1024 bf16
#define OFF_WB3   (OFF_WB2 + (size_t)HID*HID*2)
#define OFF_WB4   (OFF_WB3 + (size_t)HID*HID*2)
#define OFF_WB5   (OFF_WB4 + (size_t)HID*HID*2)        // 32x1024 bf16
#define OFF_CB    (OFF_WB5 + (size_t)OBS*HID*2)        // 256 f32 (b_ih+b_hh)
#define OFF_WHH2  (OFF_CB + (size_t)LAT*4)             // 64x256 uint2 packed W_hh^T
#define OFF_WIH2  (OFF_WHH2 + (size_t)64*256*8)        // 8x256 uint2 packed W_ih^T
#define OFF_ZF    (OFF_WIH2 + (size_t)8*256*8)         // 128x256 f32
#define OFF_Z     (OFF_ZF + (size_t)BATCH*LAT*4)       // 32768x256 bf16
#define OFF_WBC   (OFF_Z + (size_t)BATCH*TTF*LAT*2)    // 256x288 bf16 cell matrix
#define OFF_HB    (OFF_WBC + (size_t)LAT*288*2)        // 8 x 2par x 4 x 16x1024 bf16
#define OFF_CTR   (OFF_HB + (size_t)GROUPS*8*16*HID*2) // 8 x 512B counters
#define OFF_END   (OFF_CTR + (size_t)GROUPS*512)

__device__ __forceinline__ uint16_t f2bf(float f) {
    uint32_t u = __float_as_uint(f);
    u += 0x7fffu + ((u >> 16) & 1u);   // RNE
    return (uint16_t)(u >> 16);
}
__device__ __forceinline__ float bflo(uint32_t u) { return __uint_as_float(u << 16); }
__device__ __forceinline__ float bfhi(uint32_t u) { return __uint_as_float(u & 0xffff0000u); }

__device__ __forceinline__ float fast_tanh(float x) {
    float ax = fabsf(x);
    float e  = __expf(-2.f * ax);
    float r  = (1.f - e) / (1.f + e);
    return copysignf(r, x);
}

// XOR-granule swizzles (16B granule index ^ low bits of row). Producers store
// swizzled; the verbatim DMA lands swizzled in LDS; readers XOR back.
__device__ __forceinline__ int hswz(int row, int col) {   // h: stride 1024
    return row * 1024 + ((((col >> 3) ^ (row & 7)) << 3) | (col & 7));
}
__device__ __forceinline__ int zswz(int row, int col) {   // z: stride 256
    return row * 256 + ((((col >> 3) ^ (row & 7)) << 3) | (col & 7));
}

// 16B MALL-coherent store (sc0|sc1 write-through, proven R9/R10).
__device__ __forceinline__ void st16_mall(void* p, floatx4 v) {
    asm volatile("global_store_dwordx4 %0, %1, off sc0 sc1"
                 :: "v"(p), "v"(v) : "memory");
}

// async DMA global->LDS, 16 B/lane, aux=0x11 (CPol SC0|SC1): reads at MALL
// (coherent with the sc0|sc1 writers), does not allocate into L1/L2.
typedef const __attribute__((address_space(1))) void* gas_t;
typedef __attribute__((address_space(3))) void* las_t;
__device__ __forceinline__ void gl_lds16(const void* g, void* l) {
    __builtin_amdgcn_global_load_lds((gas_t)g, (las_t)l, 16, 0, 0x11);
}

// 32 KB h tile MALL -> LDS: per wave 16 issues x 1 KB, all in flight.
__device__ __forceinline__ void stage_h(const uint16_t* src, uint16_t* dst,
                                        int w, int L) {
    const char* gp = (const char*)src + w * 16384 + L * 16;
    char* lp = (char*)dst + w * 16384;
    #pragma unroll
    for (int i = 0; i < 16; i++)
        gl_lds16(gp + i * 1024, lp + i * 1024);
}

// ---------------------------------------------------------------------------
// K0 helpers
// ---------------------------------------------------------------------------
__global__ void k_cvt(const float* __restrict__ s, uint16_t* __restrict__ d, int n) {
    int i = blockIdx.x * 256 + threadIdx.x;
    if (i < n) d[i] = f2bf(s[i]);
}

__global__ void k_cb(const float* __restrict__ a, const float* __restrict__ b,
                     float* __restrict__ c) {
    int j = threadIdx.x;
    c[j] = a[j] + b[j];
}

__global__ void k_pack(const float* __restrict__ w, uint2* __restrict__ dst, int klen) {
    int k4 = blockIdx.x, j = threadIdx.x;
    int k = k4 * 4;
    uint32_t a = f2bf(w[(size_t)j * klen + k + 0]);
    uint32_t b = f2bf(w[(size_t)j * klen + k + 1]);
    uint32_t c = f2bf(w[(size_t)j * klen + k + 2]);
    uint32_t d = f2bf(w[(size_t)j * klen + k + 3]);
    uint2 r; r.x = a | (b << 16); r.y = c | (d << 16);
    dst[k4 * 256 + j] = r;
}

__global__ void k_packc(const float* __restrict__ whh, const float* __restrict__ wih,
                        uint16_t* __restrict__ wbc) {
    int col = blockIdx.x;
    for (int k = threadIdx.x; k < 288; k += 256) {
        float v = (k < 256) ? whh[(size_t)col * 256 + k] : wih[(size_t)col * 32 + (k - 256)];
        wbc[(size_t)col * 288 + k] = f2bf(v);
    }
}

// ---------------------------------------------------------------------------
// K1 (R19): teacher-forced recurrence, scalar with 4-way ILP + y prefetch.
// 128 blocks x 256 threads.
// ---------------------------------------------------------------------------
__global__ __launch_bounds__(256) void k_rnn_tf(
    const float* __restrict__ y, const uint2* __restrict__ whh2,
    const uint2* __restrict__ wih2, const float* __restrict__ cb,
    uint16_t* __restrict__ Zg, float* __restrict__ zfinal)
{
    __shared__ alignas(16) float zl[LAT];
    __shared__ alignas(16) float ys[OBS];
    int j = threadIdx.x, b = blockIdx.x;
    zl[j] = 0.f;
    const float cbj = cb[j];
    float ynext = (j < OBS) ? y[(size_t)b * (TTF * OBS) + j] : 0.f;
    __syncthreads();
    const float4* z4 = (const float4*)zl;
    const float4* y4 = (const float4*)ys;
    for (int t = 0; t < TTF; t++) {
        if (j < OBS) ys[j] = ynext;
        Zg[((size_t)b * TTF + t) * LAT + j] = f2bf(zl[j]);
        __syncthreads();
        // prefetch y[t+1] during the compute (off the critical path)
        if (t + 1 < TTF && j < OBS)
            ynext = y[(size_t)b * (TTF * OBS) + (t + 1) * OBS + j];
        // 4 independent accumulator chains (breaks the 288-FMA dependency)
        float a0 = cbj, a1 = 0.f, a2 = 0.f, a3 = 0.f;
        #pragma unroll 4
        for (int k4 = 0; k4 < 64; k4 += 4) {
            uint2 w0 = whh2[(k4 + 0) * 256 + j]; float4 z0 = z4[k4 + 0];
            uint2 w1 = whh2[(k4 + 1) * 256 + j]; float4 z1 = z4[k4 + 1];
            uint2 w2 = whh2[(k4 + 2) * 256 + j]; float4 z2 = z4[k4 + 2];
            uint2 w3 = whh2[(k4 + 3) * 256 + j]; float4 z3 = z4[k4 + 3];
            a0 += bflo(w0.x) * z0.x + bfhi(w0.x) * z0.y
                + bflo(w0.y) * z0.z + bfhi(w0.y) * z0.w;
            a1 += bflo(w1.x) * z1.x + bfhi(w1.x) * z1.y
                + bflo(w1.y) * z1.z + bfhi(w1.y) * z1.w;
            a2 += bflo(w2.x) * z2.x + bfhi(w2.x) * z2.y
                + bflo(w2.y) * z2.z + bfhi(w2.y) * z2.w;
            a3 += bflo(w3.x) * z3.x + bfhi(w3.x) * z3.y
                + bflo(w3.y) * z3.z + bfhi(w3.y) * z3.w;
        }
        #pragma unroll
        for (int k4 = 0; k4 < 8; k4 += 4) {
            uint2 w0 = wih2[(k4 + 0) * 256 + j]; float4 q0 = y4[k4 + 0];
            uint2 w1 = wih2[(k4 + 1) * 256 + j]; float4 q1 = y4[k4 + 1];
            uint2 w2 = wih2[(k4 + 2) * 256 + j]; float4 q2 = y4[k4 + 2];
            uint2 w3 = wih2[(k4 + 3) * 256 + j]; float4 q3 = y4[k4 + 3];
            a0 += bflo(w0.x) * q0.x + bfhi(w0.x) * q0.y
                + bflo(w0.y) * q0.z + bfhi(w0.y) * q0.w;
            a1 += bflo(w1.x) * q1.x + bfhi(w1.x) * q1.y
                + bflo(w1.y) * q1.z + bfhi(w1.y) * q1.w;
            a2 += bflo(w2.x) * q2.x + bfhi(w2.x) * q2.y
                + bflo(w2.y) * q2.z + bfhi(w2.y) * q2.w;
            a3 += bflo(w3.x) * q3.x + bfhi(w3.x) * q3.y
                + bflo(w3.y) * q3.z + bfhi(w3.y) * q3.w;
        }
        float acc = (a0 + a1) + (a2 + a3);
        __syncthreads();
        zl[j] = fast_tanh(acc);
    }
    __syncthreads();
    zfinal[(size_t)b * LAT + j] = zl[j];
}

// ---------------------------------------------------------------------------
// K2 primary: bulk psi, 64 rows/block (512 blocks, 512 thr, 128KB LDS).
// ---------------------------------------------------------------------------
__global__ __launch_bounds__(512) void k_psi_bulk64(
    const uint16_t* __restrict__ Zg,
    const uint16_t* __restrict__ wb1, const uint16_t* __restrict__ wb2,
    const uint16_t* __restrict__ wb3, const uint16_t* __restrict__ wb4,
    const uint16_t* __restrict__ wb5,
    const float* __restrict__ b1, const float* __restrict__ b2,
    const float* __restrict__ b3, const float* __restrict__ b4,
    const float* __restrict__ b5, float* __restrict__ out)
{
    __shared__ uint16_t hbuf[64 * 1024];   // 128 KB, swizzled
    int tid = threadIdx.x;
    int w = tid >> 6, L = tid & 63, lm = L & 15, q = L >> 4;
    int rb = blockIdx.x * 64;
    int colbase = w * 128;
    floatx4 acc[4][8];
    const floatx4 zero = {0.f, 0.f, 0.f, 0.f};

    #pragma unroll
    for (int rf = 0; rf < 4; rf++)
        #pragma unroll
        for (int nt = 0; nt < 8; nt++) acc[rf][nt] = zero;
    for (int kc = 0; kc < 8; kc++) {
        short8 a[4];
        #pragma unroll
        for (int rf = 0; rf < 4; rf++)
            a[rf] = *(const short8*)(Zg + (size_t)(rb + rf * 16 + lm) * LAT + kc * 32 + q * 8);
        #pragma unroll
        for (int nt = 0; nt < 8; nt++) {
            int n = colbase + nt * 16 + lm;
            short8 bf = *(const short8*)(wb1 + (size_t)n * LAT + kc * 32 + q * 8);
            #pragma unroll
            for (int rf = 0; rf < 4; rf++)
                acc[rf][nt] = __builtin_amdgcn_mfma_f32_16x16x32_bf16(a[rf], bf, acc[rf][nt], 0, 0, 0);
        }
    }
    #pragma unroll
    for (int rf = 0; rf < 4; rf++)
        #pragma unroll
        for (int nt = 0; nt < 8; nt++) {
            int col = colbase + nt * 16 + lm;
            float bias = b1[col];
            #pragma unroll
            for (int i = 0; i < 4; i++) {
                int row = rf * 16 + q * 4 + i;
                hbuf[hswz(row, col)] = f2bf(fmaxf(acc[rf][nt][i] + bias, 0.f));
            }
        }
    __syncthreads();

    const uint16_t* wbs[3] = {wb2, wb3, wb4};
    const float*    bbs[3] = {b2, b3, b4};
    for (int ll = 0; ll < 3; ll++) {
        const uint16_t* wb = wbs[ll];
        const float* bb = bbs[ll];
        #pragma unroll
        for (int rf = 0; rf < 4; rf++)
            #pragma unroll
            for (int nt = 0; nt < 8; nt++) acc[rf][nt] = zero;
        for (int kc = 0; kc < 32; kc++) {
            int g = ((kc * 4 + q) ^ (lm & 7)) << 3;
            short8 a[4];
            #pragma unroll
            for (int rf = 0; rf < 4; rf++)
                a[rf] = *(const short8*)(hbuf + (rf * 16 + lm) * 1024 + g);
            #pragma unroll
            for (int nt = 0; nt < 8; nt++) {
                int n = colbase + nt * 16 + lm;
                short8 bf = *(const short8*)(wb + (size_t)n * HID + kc * 32 + q * 8);
                #pragma unroll
                for (int rf = 0; rf < 4; rf++)
                    acc[rf][nt] = __builtin_amdgcn_mfma_f32_16x16x32_bf16(a[rf], bf, acc[rf][nt], 0, 0, 0);
            }
        }
        __syncthreads();
        #pragma unroll
        for (int rf = 0; rf < 4; rf++)
            #pragma unroll
            for (int nt = 0; nt < 8; nt++) {
                int col = colbase + nt * 16 + lm;
                float bias = bb[col];
                #pragma unroll
                for (int i = 0; i < 4; i++) {
                    int row = rf * 16 + q * 4 + i;
                    hbuf[hswz(row, col)] = f2bf(fmaxf(acc[rf][nt][i] + bias, 0.f));
                }
            }
        __syncthreads();
    }

    // L5: all 8 waves -- wave w = row-frag (w>>1) x col-tile (w&1)
    {
        int rf5 = w >> 1;
        int nb = (w & 1) * 16;
        floatx4 a5 = zero;
        for (int kc = 0; kc < 32; kc++) {
            int g = ((kc * 4 + q) ^ (lm & 7)) << 3;
            short8 a = *(const short8*)(hbuf + (rf5 * 16 + lm) * 1024 + g);
            short8 bf = *(const short8*)(wb5 + (size_t)(nb + lm) * HID + kc * 32 + q * 8);
            a5 = __builtin_amdgcn_mfma_f32_16x16x32_bf16(a, bf, a5, 0, 0, 0);
        }
        int col = nb + lm;
        float bias = b5[col];
        #pragma unroll
        for (int i = 0; i < 4; i++) {
            int r = rb + rf5 * 16 + q * 4 + i;
            int bb_ = r >> 8, tt = r & 255;
            out[(size_t)bb_ * (HOR * OBS) + tt * OBS + col] = a5[i] + bias;
        }
    }
}

// ---------------------------------------------------------------------------
// K2 fallback: bulk psi, 32 rows/block (R10-proven). Launched only if the
// 64-row variant is rejected at launch (synchronous error check).
// ---------------------------------------------------------------------------
__global__ __launch_bounds__(512) void k_psi_bulk(
    const uint16_t* __restrict__ Zg,
    const uint16_t* __restrict__ wb1, const uint16_t* __restrict__ wb2,
    const uint16_t* __restrict__ wb3, const uint16_t* __restrict__ wb4,
    const uint16_t* __restrict__ wb5,
    const float* __restrict__ b1, const float* __restrict__ b2,
    const float* __restrict__ b3, const float* __restrict__ b4,
    const float* __restrict__ b5, float* __restrict__ out)
{
    __shared__ uint16_t hbuf[32 * 1024];   // 64 KB, swizzled
    int tid = threadIdx.x;
    int w = tid >> 6, L = tid & 63, lm = L & 15, q = L >> 4;
    int rb = blockIdx.x * 32;
    int colbase = w * 128;
    floatx4 acc[2][8];
    const floatx4 zero = {0.f, 0.f, 0.f, 0.f};

    #pragma unroll
    for (int mt = 0; mt < 2; mt++)
        #pragma unroll
        for (int nt = 0; nt < 8; nt++) acc[mt][nt] = zero;
    for (int kc = 0; kc < 8; kc++) {
        short8 a0 = *(const short8*)(Zg + (size_t)(rb + lm) * LAT + kc * 32 + q * 8);
        short8 a1 = *(const short8*)(Zg + (size_t)(rb + 16 + lm) * LAT + kc * 32 + q * 8);
        #pragma unroll
        for (int nt = 0; nt < 8; nt++) {
            int n = colbase + nt * 16 + lm;
            short8 bf = *(const short8*)(wb1 + (size_t)n * LAT + kc * 32 + q * 8);
            acc[0][nt] = __builtin_amdgcn_mfma_f32_16x16x32_bf16(a0, bf, acc[0][nt], 0, 0, 0);
            acc[1][nt] = __builtin_amdgcn_mfma_f32_16x16x32_bf16(a1, bf, acc[1][nt], 0, 0, 0);
        }
    }
    #pragma unroll
    for (int mt = 0; mt < 2; mt++)
        #pragma unroll
        for (int nt = 0; nt < 8; nt++) {
            int col = colbase + nt * 16 + lm;
            float bias = b1[col];
            #pragma unroll
            for (int i = 0; i < 4; i++) {
                int row = mt * 16 + q * 4 + i;
                hbuf[hswz(row, col)] = f2bf(fmaxf(acc[mt][nt][i] + bias, 0.f));
            }
        }
    __syncthreads();

    const uint16_t* wbs[3] = {wb2, wb3, wb4};
    const float*    bbs[3] = {b2, b3, b4};
    for (int ll = 0; ll < 3; ll++) {
        const uint16_t* wb = wbs[ll];
        const float* bb = bbs[ll];
        #pragma unroll
        for (int mt = 0; mt < 2; mt++)
            #pragma unroll
            for (int nt = 0; nt < 8; nt++) acc[mt][nt] = zero;
        for (int kc = 0; kc < 32; kc++) {
            int g = ((kc * 4 + q) ^ (lm & 7)) << 3;
            short8 a0 = *(const short8*)(hbuf + lm * 1024 + g);
            short8 a1 = *(const short8*)(hbuf + (16 + lm) * 1024 + g);
            #pragma unroll
            for (int nt = 0; nt < 8; nt++) {
                int n = colbase + nt * 16 + lm;
                short8 bf = *(const short8*)(wb + (size_t)n * HID + kc * 32 + q * 8);
                acc[0][nt] = __builtin_amdgcn_mfma_f32_16x16x32_bf16(a0, bf, acc[0][nt], 0, 0, 0);
                acc[1][nt] = __builtin_amdgcn_mfma_f32_16x16x32_bf16(a1, bf, acc[1][nt], 0, 0, 0);
            }
        }
        __syncthreads();
        #pragma unroll
        for (int mt = 0; mt < 2; mt++)
            #pragma unroll
            for (int nt = 0; nt < 8; nt++) {
                int col = colbase + nt * 16 + lm;
                float bias = bb[col];
                #pragma unroll
                for (int i = 0; i < 4; i++) {
                    int row = mt * 16 + q * 4 + i;
                    hbuf[hswz(row, col)] = f2bf(fmaxf(acc[mt][nt][i] + bias, 0.f));
                }
            }
        __syncthreads();
    }

    if (w < 4) {
        int mt = w >> 1;
        int nb = (w & 1) * 16;
        floatx4 a5 = zero;
        for (int kc = 0; kc < 32; kc++) {
            int g = ((kc * 4 + q) ^ (lm & 7)) << 3;
            short8 a = *(const short8*)(hbuf + (mt * 16 + lm) * 1024 + g);
            short8 bf = *(const short8*)(wb5 + (size_t)(nb + lm) * HID + kc * 32 + q * 8);
            a5 = __builtin_amdgcn_mfma_f32_16x16x32_bf16(a, bf, a5, 0, 0, 0);
        }
        int col = nb + lm;
        float bias = b5[col];
        #pragma unroll
        for (int i = 0; i < 4; i++) {
            int row = mt * 16 + q * 4 + i;
            int r = rb + row;
            int bb_ = r >> 8, tt = r & 255;
            out[(size_t)bb_ * (HOR * OBS) + tt * OBS + col] = a5[i] + bias;
        }
    }
}

// ---------------------------------------------------------------------------
// K3 v15 (R20): persistent AR. R14 hop structure with SPLIT-PUBLISH arrive:
// each wave publishes its own 16-col half (granules {2w,2w+1}), drains, and
// its lane0 arrives (target 64/hop). No pre-publish barrier. CCZ overlap +
// WAIT (tid0 spin + 1 syncthreads) + DMA + syncthreads unchanged.
// ---------------------------------------------------------------------------
__global__ __launch_bounds__(ARTHREADS) void k_ar2(
    const float* __restrict__ zfinal,
    const uint16_t* __restrict__ wb1, const uint16_t* __restrict__ wb2,
    const uint16_t* __restrict__ wb3, const uint16_t* __restrict__ wb4,
    const uint16_t* __restrict__ wb5, const uint16_t* __restrict__ wbc,
    const float* __restrict__ b1g, const float* __restrict__ b2g,
    const float* __restrict__ b3g, const float* __restrict__ b4g,
    const float* __restrict__ b5g, const float* __restrict__ cb,
    uint16_t* __restrict__ hb_all, unsigned* __restrict__ ctr_all,
    float* __restrict__ out)
{
    __shared__ alignas(16) uint16_t hstg[16 * 1024];   // 32 KB staged h tile
    __shared__ alignas(16) uint16_t zst[2 * 16 * 256]; // 16 KB z parity buffers
    __shared__ alignas(16) uint16_t yscr[16 * 32];     // 1 KB
    __shared__ alignas(16) uint16_t hsl[16 * 32];      // 1 KB slice transpose

    const int tid = threadIdx.x;
    const int g = blockIdx.x >> 5, m = blockIdx.x & 31;   // member m -> XCD m%8
    const int w = tid >> 6, L = tid & 63, lm = L & 15, q = L >> 4, lm7 = lm & 7;
    const int colbase = m * 32;
    const int cl = w * 16 + lm;
    const int rb = g * 16;
    uint16_t* hb = hb_all + (size_t)g * (8 * 16 * HID);   // 2 parity x 4 slots
    unsigned* ctr = ctr_all + g * 128;
    const floatx4 zero = {0.f, 0.f, 0.f, 0.f};

    // loop-invariant bias loads, hoisted out of the t-loop
    const float b1v = b1g[colbase + cl];
    const float b2v = b2g[colbase + cl];
    const float b3v = b3g[colbase + cl];
    const float b4v = b4g[colbase + cl];
    const float b5v = b5g[cl];
    float cbv[8];
    #pragma unroll
    for (int ct = 0; ct < 8; ct++) cbv[ct] = cb[w * 128 + ct * 16 + lm];

    // initial z: local LDS only (every member keeps its own copy), swizzled
    for (int idx = tid; idx < 16 * 256; idx += ARTHREADS) {
        int r = idx >> 8, c = idx & 255;
        zst[zswz(r, c)] = f2bf(zfinal[(size_t)(rb + r) * LAT + c]);
    }
    __syncthreads();

    // ARRIVE (split-publish): wave w publishes its own granule-columns
    // {2w, 2w+1} (32 x 16B stores), drains, lane0-of-wave arrives.
    // No cross-wave dependency -> no barrier here. Target = 64/hop.
    #define HOP_ARRIVE(DST) do {                                             \
        if (L < 32) {                                                        \
            int row_ = L >> 1, gr_ = (w << 1) | (L & 1);                     \
            floatx4 vv_ = *(const floatx4*)((const char*)hsl + row_ * 64 + gr_ * 16); \
            int gsw_ = (m * 4 + gr_) ^ (row_ & 7);                           \
            st16_mall((char*)(DST) + row_ * 2048 + gsw_ * 16, vv_);          \
        }                                                                    \
        asm volatile("s_waitcnt vmcnt(0)" ::: "memory");                     \
        if (L == 0)                                                          \
            __hip_atomic_fetch_add(ctr, 1u, __ATOMIC_RELAXED,                \
                                   __HIP_MEMORY_SCOPE_AGENT);                \
    } while (0)

    // WAIT: tid0 spins on the group counter, then one block barrier.
    #define HOP_WAIT(TGT) do {                                               \
        if (tid == 0) {                                                      \
            while (__hip_atomic_load(ctr, __ATOMIC_RELAXED,                  \
                                     __HIP_MEMORY_SCOPE_AGENT) < (TGT)) {}   \
        }                                                                    \
        __syncthreads();                                                     \
    } while (0)

    // cell z-part chunk: kc in [K0,K1), accumulated into cc[8]
    #define CCZ(K0, K1) do {                                                 \
        _Pragma("unroll")                                                    \
        for (int ct = 0; ct < 8; ct++) {                                     \
            const uint16_t* bb2_ = wbc + (size_t)(w * 128 + ct * 16 + lm) * 288 + q * 8; \
            _Pragma("unroll")                                                \
            for (int kc = (K0); kc < (K1); kc++) {                           \
                int gz_ = (kc * 4 + q) ^ lm7;                                \
                short8 a_ = *(const short8*)(zcur + lm * 256 + gz_ * 8);     \
                short8 b_ = *(const short8*)(bb2_ + kc * 32);                \
                cc[ct] = __builtin_amdgcn_mfma_f32_16x16x32_bf16(a_, b_, cc[ct], 0, 0, 0); \
            }                                                                \
        }                                                                    \
    } while (0)

    #define MID_COMPUTE(WB, BV) do {                                         \
        floatx4 acc_ = zero;                                                 \
        const uint16_t* bb_ = WB + (size_t)(colbase + cl) * HID + q * 8;     \
        _Pragma("unroll 8")                                                  \
        for (int kc = 0; kc < 32; kc++) {                                    \
            int gh = (kc * 4 + q) ^ lm7;                                     \
            short8 a_ = *(const short8*)(hstg + lm * 1024 + gh * 8);         \
            short8 b_ = *(const short8*)(bb_ + kc * 32);                     \
            acc_ = __builtin_amdgcn_mfma_f32_16x16x32_bf16(a_, b_, acc_, 0, 0, 0); \
        }                                                                    \
        _Pragma("unroll")                                                    \
        for (int i = 0; i < 4; i++)                                          \
            hsl[(q * 4 + i) * 32 + cl] = f2bf(fmaxf(acc_[i] + (BV), 0.f));   \
    } while (0)

    unsigned tgt = 0;
    #pragma unroll 1
    for (int t = 0; t < HOR - TTF; t++) {
        uint16_t* zcur = zst + (t & 1) * (16 * 256);
        uint16_t* znx  = zst + ((t + 1) & 1) * (16 * 256);
        uint16_t* hp = hb + (t & 1) * (4 * 16 * HID);     // step-parity tiles
        uint16_t* h1 = hp;
        uint16_t* h2 = hp + 16 * HID;
        uint16_t* h3 = hp + 2 * 16 * HID;
        uint16_t* h4 = hp + 3 * 16 * HID;

        floatx4 cc[8];
        #pragma unroll
        for (int ct = 0; ct < 8; ct++) cc[ct] = zero;

        // ---- L1 slice from LDS z (local) ----
        {
            floatx4 acc = zero;
            const uint16_t* bb = wb1 + (size_t)(colbase + cl) * LAT + q * 8;
            #pragma unroll
            for (int kc = 0; kc < 8; kc++) {
                int gz = (kc * 4 + q) ^ lm7;
                short8 a = *(const short8*)(zcur + lm * 256 + gz * 8);
                short8 b = *(const short8*)(bb + kc * 32);
                acc = __builtin_amdgcn_mfma_f32_16x16x32_bf16(a, b, acc, 0, 0, 0);
            }
            #pragma unroll
            for (int i = 0; i < 4; i++)
                hsl[(q * 4 + i) * 32 + cl] = f2bf(fmaxf(acc[i] + b1v, 0.f));
        }
        HOP_ARRIVE(h1); tgt += 2 * MEMBERS;
        CCZ(0, 2);
        HOP_WAIT(tgt);
        stage_h(h1, hstg, w, L);
        __syncthreads();

        MID_COMPUTE(wb2, b2v);
        HOP_ARRIVE(h2); tgt += 2 * MEMBERS;
        CCZ(2, 4);
        HOP_WAIT(tgt);
        stage_h(h2, hstg, w, L);
        __syncthreads();

        MID_COMPUTE(wb3, b3v);
        HOP_ARRIVE(h3); tgt += 2 * MEMBERS;
        CCZ(4, 6);
        HOP_WAIT(tgt);
        stage_h(h3, hstg, w, L);
        __syncthreads();

        MID_COMPUTE(wb4, b4v);
        HOP_ARRIVE(h4); tgt += 2 * MEMBERS;
        CCZ(6, 8);
        HOP_WAIT(tgt);
        stage_h(h4, hstg, w, L);
        __syncthreads();

        // ---- tail: L5 (redundant), out, cell finish (yh term) ----
        {
            floatx4 a5 = zero;
            const uint16_t* bb = wb5 + (size_t)cl * HID + q * 8;
            #pragma unroll 8
            for (int kc = 0; kc < 32; kc++) {
                int gh = (kc * 4 + q) ^ lm7;
                short8 a = *(const short8*)(hstg + lm * 1024 + gh * 8);
                short8 b = *(const short8*)(bb + kc * 32);
                a5 = __builtin_amdgcn_mfma_f32_16x16x32_bf16(a, b, a5, 0, 0, 0);
            }
            float vout[4];
            #pragma unroll
            for (int i = 0; i < 4; i++) {
                float v = a5[i] + b5v;
                vout[i] = v;
                yscr[(q * 4 + i) * 32 + cl] = f2bf(v);
            }
            if (m == 0) {
                #pragma unroll
                for (int i = 0; i < 4; i++)
                    out[(size_t)(rb + q * 4 + i) * (HOR * OBS) + (TTF + t) * OBS + cl] = vout[i];
            }
        }
        __syncthreads();
        // cell finish: add the yh term (kc=8) to cc[], tanh, write z'
        {
            short8 ay = *(const short8*)(yscr + lm * 32 + q * 8);
            #pragma unroll
            for (int ct = 0; ct < 8; ct++) {
                int ccol = w * 128 + ct * 16 + lm;
                const uint16_t* bb2 = wbc + (size_t)ccol * 288 + q * 8;
                short8 b = *(const short8*)(bb2 + 8 * 32);
                floatx4 v = __builtin_amdgcn_mfma_f32_16x16x32_bf16(ay, b, cc[ct], 0, 0, 0);
                #pragma unroll
                for (int i = 0; i < 4; i++)
                    znx[zswz(q * 4 + i, ccol)] = f2bf(fast_tanh(v[i] + cbv[ct]));
            }
        }
        __syncthreads();
    }
    #undef MID_COMPUTE
    #undef CCZ
    #undef HOP_WAIT
    #undef HOP_ARRIVE
}

// ---------------------------------------------------------------------------
extern "C" void kernel_launch(void* const* d_in, const int* in_sizes, int n_in,
                              void* d_out, int out_size, void* d_ws, size_t ws_size,
                              hipStream_t stream) {
    (void)in_sizes; (void)n_in; (void)out_size; (void)ws_size;
    const float* y    = (const float*)d_in[0];
    const float* W_ih = (const float*)d_in[2];
    const float* W_hh = (const float*)d_in[3];
    const float* b_ih = (const float*)d_in[4];
    const float* b_hh = (const float*)d_in[5];
    const float* W1   = (const float*)d_in[6];
    const float* b1   = (const float*)d_in[7];
    const float* W2   = (const float*)d_in[8];
    const float* b2   = (const float*)d_in[9];
    const float* W3   = (const float*)d_in[10];
    const float* b3   = (const float*)d_in[11];
    const float* W4   = (const float*)d_in[12];
    const float* b4   = (const float*)d_in[13];
    const float* W5   = (const float*)d_in[14];
    const float* b5   = (const float*)d_in[15];
    float* out = (float*)d_out;
    char* ws = (char*)d_ws;

    uint16_t* WB1  = (uint16_t*)(ws + OFF_WB1);
    uint16_t* WB2  = (uint16_t*)(ws + OFF_WB2);
    uint16_t* WB3  = (uint16_t*)(ws + OFF_WB3);
    uint16_t* WB4  = (uint16_t*)(ws + OFF_WB4);
    uint16_t* WB5  = (uint16_t*)(ws + OFF_WB5);
    float*    CB   = (float*)(ws + OFF_CB);
    uint2*    WHH2 = (uint2*)(ws + OFF_WHH2);
    uint2*    WIH2 = (uint2*)(ws + OFF_WIH2);
    float*    ZF   = (float*)(ws + OFF_ZF);
    uint16_t* Zbuf = (uint16_t*)(ws + OFF_Z);
    uint16_t* WBC  = (uint16_t*)(ws + OFF_WBC);
    uint16_t* HB   = (uint16_t*)(ws + OFF_HB);
    unsigned* CTR  = (unsigned*)(ws + OFF_CTR);

    k_cvt<<<(HID*LAT + 255) / 256, 256, 0, stream>>>(W1, WB1, HID * LAT);
    k_cvt<<<(HID*HID + 255) / 256, 256, 0, stream>>>(W2, WB2, HID * HID);
    k_cvt<<<(HID*HID + 255) / 256, 256, 0, stream>>>(W3, WB3, HID * HID);
    k_cvt<<<(HID*HID + 255) / 256, 256, 0, stream>>>(W4, WB4, HID * HID);
    k_cvt<<<(OBS*HID + 255) / 256, 256, 0, stream>>>(W5, WB5, OBS * HID);
    k_cb<<<1, 256, 0, stream>>>(b_ih, b_hh, CB);
    k_pack<<<64, 256, 0, stream>>>(W_hh, WHH2, LAT);
    k_pack<<<8, 256, 0, stream>>>(W_ih, WIH2, OBS);
    k_packc<<<256, 256, 0, stream>>>(W_hh, W_ih, WBC);
    hipMemsetAsync(CTR, 0, GROUPS * 512, stream);

    k_rnn_tf<<<BATCH, 256, 0, stream>>>(y, WHH2, WIH2, CB, Zbuf, ZF);

    // psi: 64-row blocks (halved weight traffic); fall back to the proven
    // 32-row version on any synchronous launch error (e.g. LDS rejection).
    k_psi_bulk64<<<(BATCH * TTF) / 64, 512, 0, stream>>>(
        Zbuf, WB1, WB2, WB3, WB4, WB5, b1, b2, b3, b4, b5, out);
    hipError_t pe = hipGetLastError();
    if (pe != hipSuccess) {
        k_psi_bulk<<<(BATCH * TTF) / 32, 512, 0, stream>>>(
            Zbuf, WB1, WB2, WB3, WB4, WB5, b1, b2, b3, b4, b5, out);
    }

    // Cooperative launch preferred (guaranteed co-residency); on ANY error
    // fall back to a plain launch — 256 blocks at 1+/CU are co-resident.
    void* args[] = {
        (void*)&ZF, (void*)&WB1, (void*)&WB2, (void*)&WB3, (void*)&WB4,
        (void*)&WB5, (void*)&WBC, (void*)&b1, (void*)&b2, (void*)&b3,
        (void*)&b4, (void*)&b5, (void*)&CB, (void*)&HB, (void*)&CTR,
        (void*)&out
    };
    hipError_t ce = hipLaunchCooperativeKernel((const void*)k_ar2,
                                               dim3(ARBLOCKS), dim3(ARTHREADS),
                                               args, 0, stream);
    if (ce != hipSuccess) {
        (void)hipGetLastError();   // clear sticky error
        k_ar2<<<dim3(ARBLOCKS), dim3(ARTHREADS), 0, stream>>>(
            ZF, WB1, WB2, WB3, WB4, WB5, WBC, b1, b2, b3, b4, b5, CB,
            HB, CTR, out);
    }
}

// Round 13
// 6177.050 us; speedup vs baseline: 1.0025x; 1.0025x over previous
//
#include <hip/hip_runtime.h>
#include <stdint.h>

// ---------------------------------------------------------------------------
// RNN rollout. Phase 1: teacher-forced recurrence (scalar, K-split halves +
// 4-way ILP, R21) + bulk psi (64-row blocks, R17). Phase 2: persistent AR
// kernel, 8 groups x 32 members, member m -> XCD m%8 (weight slices
// L2-resident, R6/R8). AR = R14/R19 structure VERBATIM (4751us steady, best
// known). Sync-structure verdict (R13 flags -9%, R14 arrive/wait +13%, R20
// split-publish null): hop cost is MALL visibility-RTT + skew; barrier
// micro-structure is exhausted. Failed variants (do not retry): co-located
// groups (R9), in-grid psi fusion (R11), redundant full-L1 (R12), epoch
// flags (R13), MALL-atomic L5 reduction (R15), chunked psi GEMMs (R16),
// MFMA TF recurrence (R18).
// R21 change (k_rnn_tf only): K-split across two 256-thread halves
// (512 thr/block): half h does z-quads [32h,32h+32) + y-quads [4h,4h+4)
// (144 FMA, ~36-deep chain at ILP4), half1 -> LDS partial, half0 sums +
// tanh. Same 2 barriers/step; 8 waves/block hide whh2 load latency.
// Sizes fixed: B=128, T=256, HOR=512, OBS=32, LAT=256, HID=1024.
// ---------------------------------------------------------------------------

#define BATCH 128
#define TTF   256
#define HOR   512
#define OBS   32
#define LAT   256
#define HID   1024

#define GROUPS  8
#define MEMBERS 32
#define ARBLOCKS (GROUPS * MEMBERS)
#define ARTHREADS 128

typedef __attribute__((ext_vector_type(8))) short short8;
typedef __attribute__((ext_vector_type(4))) float floatx4;

// ---- workspace layout (bytes) ----
#define OFF_WB1   ((size_t)0)                          // 1024x256 bf16 ([col][k])
#define OFF_WB2   (OFF_WB1 + (size_t)HID*LAT*2)        // 1024x1024 bf16
#define OFF_WB3   (OFF_WB2 + (size_t)HID*HID*2)
#define OFF_WB4   (OFF_WB3 + (size_t)HID*HID*2)
#define OFF_WB5   (OFF_WB4 + (size_t)HID*HID*2)        // 32x1024 bf16
#define OFF_CB    (OFF_WB5 + (size_t)OBS*HID*2)        // 256 f32 (b_ih+b_hh)
#define OFF_WHH2  (OFF_CB + (size_t)LAT*4)             // 64x256 uint2 packed W_hh^T
#define OFF_WIH2  (OFF_WHH2 + (size_t)64*256*8)        // 8x256 uint2 packed W_ih^T
#define OFF_ZF    (OFF_WIH2 + (size_t)8*256*8)         // 128x256 f32
#define OFF_Z     (OFF_ZF + (size_t)BATCH*LAT*4)       // 32768x256 bf16
#define OFF_WBC   (OFF_Z + (size_t)BATCH*TTF*LAT*2)    // 256x288 bf16 cell matrix
#define OFF_HB    (OFF_WBC + (size_t)LAT*288*2)        // 8 x 2par x 4 x 16x1024 bf16
#define OFF_CTR   (OFF_HB + (size_t)GROUPS*8*16*HID*2) // 8 x 512B counters
#define OFF_END   (OFF_CTR + (size_t)GROUPS*512)

__device__ __forceinline__ uint16_t f2bf(float f) {
    uint32_t u = __float_as_uint(f);
    u += 0x7fffu + ((u >> 16) & 1u);   // RNE
    return (uint16_t)(u >> 16);
}
__device__ __forceinline__ float bflo(uint32_t u) { return __uint_as_float(u << 16); }
__device__ __forceinline__ float bfhi(uint32_t u) { return __uint_as_float(u & 0xffff0000u); }

__device__ __forceinline__ float fast_tanh(float x) {
    float ax = fabsf(x);
    float e  = __expf(-2.f * ax);
    float r  = (1.f - e) / (1.f + e);
    return copysignf(r, x);
}

// XOR-granule swizzles (16B granule index ^ low bits of row). Producers store
// swizzled; the verbatim DMA lands swizzled in LDS; readers XOR back.
__device__ __forceinline__ int hswz(int row, int col) {   // h: stride 1024
    return row * 1024 + ((((col >> 3) ^ (row & 7)) << 3) | (col & 7));
}
__device__ __forceinline__ int zswz(int row, int col) {   // z: stride 256
    return row * 256 + ((((col >> 3) ^ (row & 7)) << 3) | (col & 7));
}

// 16B MALL-coherent store (sc0|sc1 write-through, proven R9/R10).
__device__ __forceinline__ void st16_mall(void* p, floatx4 v) {
    asm volatile("global_store_dwordx4 %0, %1, off sc0 sc1"
                 :: "v"(p), "v"(v) : "memory");
}

// async DMA global->LDS, 16 B/lane, aux=0x11 (CPol SC0|SC1): reads at MALL
// (coherent with the sc0|sc1 writers), does not allocate into L1/L2.
typedef const __attribute__((address_space(1))) void* gas_t;
typedef __attribute__((address_space(3))) void* las_t;
__device__ __forceinline__ void gl_lds16(const void* g, void* l) {
    __builtin_amdgcn_global_load_lds((gas_t)g, (las_t)l, 16, 0, 0x11);
}

// 32 KB h tile MALL -> LDS: per wave 16 issues x 1 KB, all in flight.
__device__ __forceinline__ void stage_h(const uint16_t* src, uint16_t* dst,
                                        int w, int L) {
    const char* gp = (const char*)src + w * 16384 + L * 16;
    char* lp = (char*)dst + w * 16384;
    #pragma unroll
    for (int i = 0; i < 16; i++)
        gl_lds16(gp + i * 1024, lp + i * 1024);
}

// ---------------------------------------------------------------------------
// K0 helpers
// ---------------------------------------------------------------------------
__global__ void k_cvt(const float* __restrict__ s, uint16_t* __restrict__ d, int n) {
    int i = blockIdx.x * 256 + threadIdx.x;
    if (i < n) d[i] = f2bf(s[i]);
}

__global__ void k_cb(const float* __restrict__ a, const float* __restrict__ b,
                     float* __restrict__ c) {
    int j = threadIdx.x;
    c[j] = a[j] + b[j];
}

__global__ void k_pack(const float* __restrict__ w, uint2* __restrict__ dst, int klen) {
    int k4 = blockIdx.x, j = threadIdx.x;
    int k = k4 * 4;
    uint32_t a = f2bf(w[(size_t)j * klen + k + 0]);
    uint32_t b = f2bf(w[(size_t)j * klen + k + 1]);
    uint32_t c = f2bf(w[(size_t)j * klen + k + 2]);
    uint32_t d = f2bf(w[(size_t)j * klen + k + 3]);
    uint2 r; r.x = a | (b << 16); r.y = c | (d << 16);
    dst[k4 * 256 + j] = r;
}

__global__ void k_packc(const float* __restrict__ whh, const float* __restrict__ wih,
                        uint16_t* __restrict__ wbc) {
    int col = blockIdx.x;
    for (int k = threadIdx.x; k < 288; k += 256) {
        float v = (k < 256) ? whh[(size_t)col * 256 + k] : wih[(size_t)col * 32 + (k - 256)];
        wbc[(size_t)col * 288 + k] = f2bf(v);
    }
}

// ---------------------------------------------------------------------------
// K1 (R21): teacher-forced recurrence, K-split halves. 128 blocks x 512 thr.
// half h: z-quads [32h,32h+32) + y-quads [4h,4h+4) with 4-way ILP; half1
// writes its partial to LDS; half0 sums + tanh. 2 barriers/step.
// ---------------------------------------------------------------------------
__global__ __launch_bounds__(512) void k_rnn_tf(
    const float* __restrict__ y, const uint2* __restrict__ whh2,
    const uint2* __restrict__ wih2, const float* __restrict__ cb,
    uint16_t* __restrict__ Zg, float* __restrict__ zfinal)
{
    __shared__ alignas(16) float zl[LAT];
    __shared__ alignas(16) float ys[OBS];
    __shared__ alignas(16) float part[256];
    const int tid = threadIdx.x;
    const int j = tid & 255, h = tid >> 8, b = blockIdx.x;
    if (h == 0) zl[j] = 0.f;
    const float cbj = (h == 0) ? cb[j] : 0.f;
    float ynext = (h == 0 && j < OBS) ? y[(size_t)b * (TTF * OBS) + j] : 0.f;
    __syncthreads();
    const float4* z4 = (const float4*)zl;
    const float4* y4 = (const float4*)ys;
    const int kb = h * 32;      // z-quad base for this half
    const int yb = h * 4;       // y-quad base for this half
    for (int t = 0; t < TTF; t++) {
        if (h == 0) {
            if (j < OBS) ys[j] = ynext;
            Zg[((size_t)b * TTF + t) * LAT + j] = f2bf(zl[j]);
        }
        __syncthreads();
        // prefetch y[t+1] during the compute (off the critical path)
        if (h == 0 && t + 1 < TTF && j < OBS)
            ynext = y[(size_t)b * (TTF * OBS) + (t + 1) * OBS + j];
        // this half's 144-FMA share, 4 independent chains
        float a0 = cbj, a1 = 0.f, a2 = 0.f, a3 = 0.f;
        #pragma unroll 4
        for (int k4 = kb; k4 < kb + 32; k4 += 4) {
            uint2 w0 = whh2[(k4 + 0) * 256 + j]; float4 z0 = z4[k4 + 0];
            uint2 w1 = whh2[(k4 + 1) * 256 + j]; float4 z1 = z4[k4 + 1];
            uint2 w2 = whh2[(k4 + 2) * 256 + j]; float4 z2 = z4[k4 + 2];
            uint2 w3 = whh2[(k4 + 3) * 256 + j]; float4 z3 = z4[k4 + 3];
            a0 += bflo(w0.x) * z0.x + bfhi(w0.x) * z0.y
                + bflo(w0.y) * z0.z + bfhi(w0.y) * z0.w;
            a1 += bflo(w1.x) * z1.x + bfhi(w1.x) * z1.y
                + bflo(w1.y) * z1.z + bfhi(w1.y) * z1.w;
            a2 += bflo(w2.x) * z2.x + bfhi(w2.x) * z2.y
                + bflo(w2.y) * z2.z + bfhi(w2.y) * z2.w;
            a3 += bflo(w3.x) * z3.x + bfhi(w3.x) * z3.y
                + bflo(w3.y) * z3.z + bfhi(w3.y) * z3.w;
        }
        {
            uint2 w0 = wih2[(yb + 0) * 256 + j]; float4 q0 = y4[yb + 0];
            uint2 w1 = wih2[(yb + 1) * 256 + j]; float4 q1 = y4[yb + 1];
            uint2 w2 = wih2[(yb + 2) * 256 + j]; float4 q2 = y4[yb + 2];
            uint2 w3 = wih2[(yb + 3) * 256 + j]; float4 q3 = y4[yb + 3];
            a0 += bflo(w0.x) * q0.x + bfhi(w0.x) * q0.y
                + bflo(w0.y) * q0.z + bfhi(w0.y) * q0.w;
            a1 += bflo(w1.x) * q1.x + bfhi(w1.x) * q1.y
                + bflo(w1.y) * q1.z + bfhi(w1.y) * q1.w;
            a2 += bflo(w2.x) * q2.x + bfhi(w2.x) * q2.y
                + bflo(w2.y) * q2.z + bfhi(w2.y) * q2.w;
            a3 += bflo(w3.x) * q3.x + bfhi(w3.x) * q3.y
                + bflo(w3.y) * q3.z + bfhi(w3.y) * q3.w;
        }
        float acc = (a0 + a1) + (a2 + a3);
        if (h == 1) part[j] = acc;
        __syncthreads();
        // half0 reads part (ordered by the barrier above); half1's next
        // part write is ordered after the next top-of-loop barrier, which
        // half0 only reaches after consuming part here.
        if (h == 0) zl[j] = fast_tanh(acc + part[j]);
    }
    __syncthreads();
    if (h == 0) zfinal[(size_t)b * LAT + j] = zl[j];
}

// ---------------------------------------------------------------------------
// K2 primary: bulk psi, 64 rows/block (512 blocks, 512 thr, 128KB LDS).
// ---------------------------------------------------------------------------
__global__ __launch_bounds__(512) void k_psi_bulk64(
    const uint16_t* __restrict__ Zg,
    const uint16_t* __restrict__ wb1, const uint16_t* __restrict__ wb2,
    const uint16_t* __restrict__ wb3, const uint16_t* __restrict__ wb4,
    const uint16_t* __restrict__ wb5,
    const float* __restrict__ b1, const float* __restrict__ b2,
    const float* __restrict__ b3, const float* __restrict__ b4,
    const float* __restrict__ b5, float* __restrict__ out)
{
    __shared__ uint16_t hbuf[64 * 1024];   // 128 KB, swizzled
    int tid = threadIdx.x;
    int w = tid >> 6, L = tid & 63, lm = L & 15, q = L >> 4;
    int rb = blockIdx.x * 64;
    int colbase = w * 128;
    floatx4 acc[4][8];
    const floatx4 zero = {0.f, 0.f, 0.f, 0.f};

    #pragma unroll
    for (int rf = 0; rf < 4; rf++)
        #pragma unroll
        for (int nt = 0; nt < 8; nt++) acc[rf][nt] = zero;
    for (int kc = 0; kc < 8; kc++) {
        short8 a[4];
        #pragma unroll
        for (int rf = 0; rf < 4; rf++)
            a[rf] = *(const short8*)(Zg + (size_t)(rb + rf * 16 + lm) * LAT + kc * 32 + q * 8);
        #pragma unroll
        for (int nt = 0; nt < 8; nt++) {
            int n = colbase + nt * 16 + lm;
            short8 bf = *(const short8*)(wb1 + (size_t)n * LAT + kc * 32 + q * 8);
            #pragma unroll
            for (int rf = 0; rf < 4; rf++)
                acc[rf][nt] = __builtin_amdgcn_mfma_f32_16x16x32_bf16(a[rf], bf, acc[rf][nt], 0, 0, 0);
        }
    }
    #pragma unroll
    for (int rf = 0; rf < 4; rf++)
        #pragma unroll
        for (int nt = 0; nt < 8; nt++) {
            int col = colbase + nt * 16 + lm;
            float bias = b1[col];
            #pragma unroll
            for (int i = 0; i < 4; i++) {
                int row = rf * 16 + q * 4 + i;
                hbuf[hswz(row, col)] = f2bf(fmaxf(acc[rf][nt][i] + bias, 0.f));
            }
        }
    __syncthreads();

    const uint16_t* wbs[3] = {wb2, wb3, wb4};
    const float*    bbs[3] = {b2, b3, b4};
    for (int ll = 0; ll < 3; ll++) {
        const uint16_t* wb = wbs[ll];
        const float* bb = bbs[ll];
        #pragma unroll
        for (int rf = 0; rf < 4; rf++)
            #pragma unroll
            for (int nt = 0; nt < 8; nt++) acc[rf][nt] = zero;
        for (int kc = 0; kc < 32; kc++) {
            int g = ((kc * 4 + q) ^ (lm & 7)) << 3;
            short8 a[4];
            #pragma unroll
            for (int rf = 0; rf < 4; rf++)
                a[rf] = *(const short8*)(hbuf + (rf * 16 + lm) * 1024 + g);
            #pragma unroll
            for (int nt = 0; nt < 8; nt++) {
                int n = colbase + nt * 16 + lm;
                short8 bf = *(const short8*)(wb + (size_t)n * HID + kc * 32 + q * 8);
                #pragma unroll
                for (int rf = 0; rf < 4; rf++)
                    acc[rf][nt] = __builtin_amdgcn_mfma_f32_16x16x32_bf16(a[rf], bf, acc[rf][nt], 0, 0, 0);
            }
        }
        __syncthreads();
        #pragma unroll
        for (int rf = 0; rf < 4; rf++)
            #pragma unroll
            for (int nt = 0; nt < 8; nt++) {
                int col = colbase + nt * 16 + lm;
                float bias = bb[col];
                #pragma unroll
                for (int i = 0; i < 4; i++) {
                    int row = rf * 16 + q * 4 + i;
                    hbuf[hswz(row, col)] = f2bf(fmaxf(acc[rf][nt][i] + bias, 0.f));
                }
            }
        __syncthreads();
    }

    // L5: all 8 waves -- wave w = row-frag (w>>1) x col-tile (w&1)
    {
        int rf5 = w >> 1;
        int nb = (w & 1) * 16;
        floatx4 a5 = zero;
        for (int kc = 0; kc < 32; kc++) {
            int g = ((kc * 4 + q) ^ (lm & 7)) << 3;
            short8 a = *(const short8*)(hbuf + (rf5 * 16 + lm) * 1024 + g);
            short8 bf = *(const short8*)(wb5 + (size_t)(nb + lm) * HID + kc * 32 + q * 8);
            a5 = __builtin_amdgcn_mfma_f32_16x16x32_bf16(a, bf, a5, 0, 0, 0);
        }
        int col = nb + lm;
        float bias = b5[col];
        #pragma unroll
        for (int i = 0; i < 4; i++) {
            int r = rb + rf5 * 16 + q * 4 + i;
            int bb_ = r >> 8, tt = r & 255;
            out[(size_t)bb_ * (HOR * OBS) + tt * OBS + col] = a5[i] + bias;
        }
    }
}

// ---------------------------------------------------------------------------
// K2 fallback: bulk psi, 32 rows/block (R10-proven). Launched only if the
// 64-row variant is rejected at launch (synchronous error check).
// ---------------------------------------------------------------------------
__global__ __launch_bounds__(512) void k_psi_bulk(
    const uint16_t* __restrict__ Zg,
    const uint16_t* __restrict__ wb1, const uint16_t* __restrict__ wb2,
    const uint16_t* __restrict__ wb3, const uint16_t* __restrict__ wb4,
    const uint16_t* __restrict__ wb5,
    const float* __restrict__ b1, const float* __restrict__ b2,
    const float* __restrict__ b3, const float* __restrict__ b4,
    const float* __restrict__ b5, float* __restrict__ out)
{
    __shared__ uint16_t hbuf[32 * 1024];   // 64 KB, swizzled
    int tid = threadIdx.x;
    int w = tid >> 6, L = tid & 63, lm = L & 15, q = L >> 4;
    int rb = blockIdx.x * 32;
    int colbase = w * 128;
    floatx4 acc[2][8];
    const floatx4 zero = {0.f, 0.f, 0.f, 0.f};

    #pragma unroll
    for (int mt = 0; mt < 2; mt++)
        #pragma unroll
        for (int nt = 0; nt < 8; nt++) acc[mt][nt] = zero;
    for (int kc = 0; kc < 8; kc++) {
        short8 a0 = *(const short8*)(Zg + (size_t)(rb + lm) * LAT + kc * 32 + q * 8);
        short8 a1 = *(const short8*)(Zg + (size_t)(rb + 16 + lm) * LAT + kc * 32 + q * 8);
        #pragma unroll
        for (int nt = 0; nt < 8; nt++) {
            int n = colbase + nt * 16 + lm;
            short8 bf = *(const short8*)(wb1 + (size_t)n * LAT + kc * 32 + q * 8);
            acc[0][nt] = __builtin_amdgcn_mfma_f32_16x16x32_bf16(a0, bf, acc[0][nt], 0, 0, 0);
            acc[1][nt] = __builtin_amdgcn_mfma_f32_16x16x32_bf16(a1, bf, acc[1][nt], 0, 0, 0);
        }
    }
    #pragma unroll
    for (int mt = 0; mt < 2; mt++)
        #pragma unroll
        for (int nt = 0; nt < 8; nt++) {
            int col = colbase + nt * 16 + lm;
            float bias = b1[col];
            #pragma unroll
            for (int i = 0; i < 4; i++) {
                int row = mt * 16 + q * 4 + i;
                hbuf[hswz(row, col)] = f2bf(fmaxf(acc[mt][nt][i] + bias, 0.f));
            }
        }
    __syncthreads();

    const uint16_t* wbs[3] = {wb2, wb3, wb4};
    const float*    bbs[3] = {b2, b3, b4};
    for (int ll = 0; ll < 3; ll++) {
        const uint16_t* wb = wbs[ll];
        const float* bb = bbs[ll];
        #pragma unroll
        for (int mt = 0; mt < 2; mt++)
            #pragma unroll
            for (int nt = 0; nt < 8; nt++) acc[mt][nt] = zero;
        for (int kc = 0; kc < 32; kc++) {
            int g = ((kc * 4 + q) ^ (lm & 7)) << 3;
            short8 a0 = *(const short8*)(hbuf + lm * 1024 + g);
            short8 a1 = *(const short8*)(hbuf + (16 + lm) * 1024 + g);
            #pragma unroll
            for (int nt = 0; nt < 8; nt++) {
                int n = colbase + nt * 16 + lm;
                short8 bf = *(const short8*)(wb + (size_t)n * HID + kc * 32 + q * 8);
                acc[0][nt] = __builtin_amdgcn_mfma_f32_16x16x32_bf16(a0, bf, acc[0][nt], 0, 0, 0);
                acc[1][nt] = __builtin_amdgcn_mfma_f32_16x16x32_bf16(a1, bf, acc[1][nt], 0, 0, 0);
            }
        }
        __syncthreads();
        #pragma unroll
        for (int mt = 0; mt < 2; mt++)
            #pragma unroll
            for (int nt = 0; nt < 8; nt++) {
                int col = colbase + nt * 16 + lm;
                float bias = bb[col];
                #pragma unroll
                for (int i = 0; i < 4; i++) {
                    int row = mt * 16 + q * 4 + i;
                    hbuf[hswz(row, col)] = f2bf(fmaxf(acc[mt][nt][i] + bias, 0.f));
                }
            }
        __syncthreads();
    }

    if (w < 4) {
        int mt = w >> 1;
        int nb = (w & 1) * 16;
        floatx4 a5 = zero;
        for (int kc = 0; kc < 32; kc++) {
            int g = ((kc * 4 + q) ^ (lm & 7)) << 3;
            short8 a = *(const short8*)(hbuf + (mt * 16 + lm) * 1024 + g);
            short8 bf = *(const short8*)(wb5 + (size_t)(nb + lm) * HID + kc * 32 + q * 8);
            a5 = __builtin_amdgcn_mfma_f32_16x16x32_bf16(a, bf, a5, 0, 0, 0);
        }
        int col = nb + lm;
        float bias = b5[col];
        #pragma unroll
        for (int i = 0; i < 4; i++) {
            int row = mt * 16 + q * 4 + i;
            int r = rb + row;
            int bb_ = r >> 8, tt = r & 255;
            out[(size_t)bb_ * (HOR * OBS) + tt * OBS + col] = a5[i] + bias;
        }
    }
}

// ---------------------------------------------------------------------------
// K3 v14 (R19 verbatim): persistent AR. ARRIVE (wave0 publish + drain +
// lane0 RMW) / overlap (cell z-part CCZ) / WAIT (tid0 spin + 1 barrier).
// Tail: stage h4, L5 redundant, out, cell finish. Step-parity h tiles.
// ---------------------------------------------------------------------------
__global__ __launch_bounds__(ARTHREADS) void k_ar2(
    const float* __restrict__ zfinal,
    const uint16_t* __restrict__ wb1, const uint16_t* __restrict__ wb2,
    const uint16_t* __restrict__ wb3, const uint16_t* __restrict__ wb4,
    const uint16_t* __restrict__ wb5, const uint16_t* __restrict__ wbc,
    const float* __restrict__ b1g, const float* __restrict__ b2g,
    const float* __restrict__ b3g, const float* __restrict__ b4g,
    const float* __restrict__ b5g, const float* __restrict__ cb,
    uint16_t* __restrict__ hb_all, unsigned* __restrict__ ctr_all,
    float* __restrict__ out)
{
    __shared__ alignas(16) uint16_t hstg[16 * 1024];   // 32 KB staged h tile
    __shared__ alignas(16) uint16_t zst[2 * 16 * 256]; // 16 KB z parity buffers
    __shared__ alignas(16) uint16_t yscr[16 * 32];     // 1 KB
    __shared__ alignas(16) uint16_t hsl[16 * 32];      // 1 KB slice transpose

    const int tid = threadIdx.x;
    const int g = blockIdx.x >> 5, m = blockIdx.x & 31;   // member m -> XCD m%8
    const int w = tid >> 6, L = tid & 63, lm = L & 15, q = L >> 4, lm7 = lm & 7;
    const int colbase = m * 32;
    const int cl = w * 16 + lm;
    const int rb = g * 16;
    uint16_t* hb = hb_all + (size_t)g * (8 * 16 * HID);   // 2 parity x 4 slots
    unsigned* ctr = ctr_all + g * 128;
    const floatx4 zero = {0.f, 0.f, 0.f, 0.f};

    // loop-invariant bias loads, hoisted out of the t-loop
    const float b1v = b1g[colbase + cl];
    const float b2v = b2g[colbase + cl];
    const float b3v = b3g[colbase + cl];
    const float b4v = b4g[colbase + cl];
    const float b5v = b5g[cl];
    float cbv[8];
    #pragma unroll
    for (int ct = 0; ct < 8; ct++) cbv[ct] = cb[w * 128 + ct * 16 + lm];

    // initial z: local LDS only (every member keeps its own copy), swizzled
    for (int idx = tid; idx < 16 * 256; idx += ARTHREADS) {
        int r = idx >> 8, c = idx & 255;
        zst[zswz(r, c)] = f2bf(zfinal[(size_t)(rb + r) * LAT + c]);
    }
    __syncthreads();

    // ARRIVE: wave0 publishes slice, drains its stores, lane0 RMWs counter.
    #define HOP_ARRIVE(DST) do {                                             \
        __syncthreads();                                                     \
        if (tid < 64) {                                                      \
            int row_ = tid >> 2, gr_ = tid & 3;                              \
            floatx4 vv_ = *(const floatx4*)((const char*)hsl + tid * 16);    \
            int gsw_ = (m * 4 + gr_) ^ (row_ & 7);                           \
            st16_mall((char*)(DST) + row_ * 2048 + gsw_ * 16, vv_);          \
            asm volatile("s_waitcnt vmcnt(0)" ::: "memory");                 \
            if (tid == 0)                                                    \
                __hip_atomic_fetch_add(ctr, 1u, __ATOMIC_RELAXED,            \
                                       __HIP_MEMORY_SCOPE_AGENT);            \
        }                                                                    \
    } while (0)

    // WAIT: tid0 spins on the group counter, then one block barrier.
    #define HOP_WAIT(TGT) do {                                               \
        if (tid == 0) {                                                      \
            while (__hip_atomic_load(ctr, __ATOMIC_RELAXED,                  \
                                     __HIP_MEMORY_SCOPE_AGENT) < (TGT)) {}   \
        }                                                                    \
        __syncthreads();                                                     \
    } while (0)

    // cell z-part chunk: kc in [K0,K1), accumulated into cc[8]
    #define CCZ(K0, K1) do {                                                 \
        _Pragma("unroll")                                                    \
        for (int ct = 0; ct < 8; ct++) {                                     \
            const uint16_t* bb2_ = wbc + (size_t)(w * 128 + ct * 16 + lm) * 288 + q * 8; \
            _Pragma("unroll")                                                \
            for (int kc = (K0); kc < (K1); kc++) {                           \
                int gz_ = (kc * 4 + q) ^ lm7;                                \
                short8 a_ = *(const short8*)(zcur + lm * 256 + gz_ * 8);     \
                short8 b_ = *(const short8*)(bb2_ + kc * 32);                \
                cc[ct] = __builtin_amdgcn_mfma_f32_16x16x32_bf16(a_, b_, cc[ct], 0, 0, 0); \
            }                                                                \
        }                                                                    \
    } while (0)

    #define MID_COMPUTE(WB, BV) do {                                         \
        floatx4 acc_ = zero;                                                 \
        const uint16_t* bb_ = WB + (size_t)(colbase + cl) * HID + q * 8;     \
        _Pragma("unroll 8")                                                  \
        for (int kc = 0; kc < 32; kc++) {                                    \
            int gh = (kc * 4 + q) ^ lm7;                                     \
            short8 a_ = *(const short8*)(hstg + lm * 1024 + gh * 8);         \
            short8 b_ = *(const short8*)(bb_ + kc * 32);                     \
            acc_ = __builtin_amdgcn_mfma_f32_16x16x32_bf16(a_, b_, acc_, 0, 0, 0); \
        }                                                                    \
        _Pragma("unroll")                                                    \
        for (int i = 0; i < 4; i++)                                          \
            hsl[(q * 4 + i) * 32 + cl] = f2bf(fmaxf(acc_[i] + (BV), 0.f));   \
    } while (0)

    unsigned tgt = 0;
    #pragma unroll 1
    for (int t = 0; t < HOR - TTF; t++) {
        uint16_t* zcur = zst + (t & 1) * (16 * 256);
        uint16_t* znx  = zst + ((t + 1) & 1) * (16 * 256);
        uint16_t* hp = hb + (t & 1) * (4 * 16 * HID);     // step-parity tiles
        uint16_t* h1 = hp;
        uint16_t* h2 = hp + 16 * HID;
        uint16_t* h3 = hp + 2 * 16 * HID;
        uint16_t* h4 = hp + 3 * 16 * HID;

        floatx4 cc[8];
        #pragma unroll
        for (int ct = 0; ct < 8; ct++) cc[ct] = zero;

        // ---- L1 slice from LDS z (local) ----
        {
            floatx4 acc = zero;
            const uint16_t* bb = wb1 + (size_t)(colbase + cl) * LAT + q * 8;
            #pragma unroll
            for (int kc = 0; kc < 8; kc++) {
                int gz = (kc * 4 + q) ^ lm7;
                short8 a = *(const short8*)(zcur + lm * 256 + gz * 8);
                short8 b = *(const short8*)(bb + kc * 32);
                acc = __builtin_amdgcn_mfma_f32_16x16x32_bf16(a, b, acc, 0, 0, 0);
            }
            #pragma unroll
            for (int i = 0; i < 4; i++)
                hsl[(q * 4 + i) * 32 + cl] = f2bf(fmaxf(acc[i] + b1v, 0.f));
        }
        HOP_ARRIVE(h1); tgt += MEMBERS;
        CCZ(0, 2);
        HOP_WAIT(tgt);
        stage_h(h1, hstg, w, L);
        __syncthreads();

        MID_COMPUTE(wb2, b2v);
        HOP_ARRIVE(h2); tgt += MEMBERS;
        CCZ(2, 4);
        HOP_WAIT(tgt);
        stage_h(h2, hstg, w, L);
        __syncthreads();

        MID_COMPUTE(wb3, b3v);
        HOP_ARRIVE(h3); tgt += MEMBERS;
        CCZ(4, 6);
        HOP_WAIT(tgt);
        stage_h(h3, hstg, w, L);
        __syncthreads();

        MID_COMPUTE(wb4, b4v);
        HOP_ARRIVE(h4); tgt += MEMBERS;
        CCZ(6, 8);
        HOP_WAIT(tgt);
        stage_h(h4, hstg, w, L);
        __syncthreads();

        // ---- tail: L5 (redundant), out, cell finish (yh term) ----
        {
            floatx4 a5 = zero;
            const uint16_t* bb = wb5 + (size_t)cl * HID + q * 8;
            #pragma unroll 8
            for (int kc = 0; kc < 32; kc++) {
                int gh = (kc * 4 + q) ^ lm7;
                short8 a = *(const short8*)(hstg + lm * 1024 + gh * 8);
                short8 b = *(const short8*)(bb + kc * 32);
                a5 = __builtin_amdgcn_mfma_f32_16x16x32_bf16(a, b, a5, 0, 0, 0);
            }
            float vout[4];
            #pragma unroll
            for (int i = 0; i < 4; i++) {
                float v = a5[i] + b5v;
                vout[i] = v;
                yscr[(q * 4 + i) * 32 + cl] = f2bf(v);
            }
            if (m == 0) {
                #pragma unroll
                for (int i = 0; i < 4; i++)
                    out[(size_t)(rb + q * 4 + i) * (HOR * OBS) + (TTF + t) * OBS + cl] = vout[i];
            }
        }
        __syncthreads();
        // cell finish: add the yh term (kc=8) to cc[], tanh, write z'
        {
            short8 ay = *(const short8*)(yscr + lm * 32 + q * 8);
            #pragma unroll
            for (int ct = 0; ct < 8; ct++) {
                int ccol = w * 128 + ct * 16 + lm;
                const uint16_t* bb2 = wbc + (size_t)ccol * 288 + q * 8;
                short8 b = *(const short8*)(bb2 + 8 * 32);
                floatx4 v = __builtin_amdgcn_mfma_f32_16x16x32_bf16(ay, b, cc[ct], 0, 0, 0);
                #pragma unroll
                for (int i = 0; i < 4; i++)
                    znx[zswz(q * 4 + i, ccol)] = f2bf(fast_tanh(v[i] + cbv[ct]));
            }
        }
        __syncthreads();
    }
    #undef MID_COMPUTE
    #undef CCZ
    #undef HOP_WAIT
    #undef HOP_ARRIVE
}

// ---------------------------------------------------------------------------
extern "C" void kernel_launch(void* const* d_in, const int* in_sizes, int n_in,
                              void* d_out, int out_size, void* d_ws, size_t ws_size,
                              hipStream_t stream) {
    (void)in_sizes; (void)n_in; (void)out_size; (void)ws_size;
    const float* y    = (const float*)d_in[0];
    const float* W_ih = (const float*)d_in[2];
    const float* W_hh = (const float*)d_in[3];
    const float* b_ih = (const float*)d_in[4];
    const float* b_hh = (const float*)d_in[5];
    const float* W1   = (const float*)d_in[6];
    const float* b1   = (const float*)d_in[7];
    const float* W2   = (const float*)d_in[8];
    const float* b2   = (const float*)d_in[9];
    const float* W3   = (const float*)d_in[10];
    const float* b3   = (const float*)d_in[11];
    const float* W4   = (const float*)d_in[12];
    const float* b4   = (const float*)d_in[13];
    const float* W5   = (const float*)d_in[14];
    const float* b5   = (const float*)d_in[15];
    float* out = (float*)d_out;
    char* ws = (char*)d_ws;

    uint16_t* WB1  = (uint16_t*)(ws + OFF_WB1);
    uint16_t* WB2  = (uint16_t*)(ws + OFF_WB2);
    uint16_t* WB3  = (uint16_t*)(ws + OFF_WB3);
    uint16_t* WB4  = (uint16_t*)(ws + OFF_WB4);
    uint16_t* WB5  = (uint16_t*)(ws + OFF_WB5);
    float*    CB   = (float*)(ws + OFF_CB);
    uint2*    WHH2 = (uint2*)(ws + OFF_WHH2);
    uint2*    WIH2 = (uint2*)(ws + OFF_WIH2);
    float*    ZF   = (float*)(ws + OFF_ZF);
    uint16_t* Zbuf = (uint16_t*)(ws + OFF_Z);
    uint16_t* WBC  = (uint16_t*)(ws + OFF_WBC);
    uint16_t* HB   = (uint16_t*)(ws + OFF_HB);
    unsigned* CTR  = (unsigned*)(ws + OFF_CTR);

    k_cvt<<<(HID*LAT + 255) / 256, 256, 0, stream>>>(W1, WB1, HID * LAT);
    k_cvt<<<(HID*HID + 255) / 256, 256, 0, stream>>>(W2, WB2, HID * HID);
    k_cvt<<<(HID*HID + 255) / 256, 256, 0, stream>>>(W3, WB3, HID * HID);
    k_cvt<<<(HID*HID + 255) / 256, 256, 0, stream>>>(W4, WB4, HID * HID);
    k_cvt<<<(OBS*HID + 255) / 256, 256, 0, stream>>>(W5, WB5, OBS * HID);
    k_cb<<<1, 256, 0, stream>>>(b_ih, b_hh, CB);
    k_pack<<<64, 256, 0, stream>>>(W_hh, WHH2, LAT);
    k_pack<<<8, 256, 0, stream>>>(W_ih, WIH2, OBS);
    k_packc<<<256, 256, 0, stream>>>(W_hh, W_ih, WBC);
    hipMemsetAsync(CTR, 0, GROUPS * 512, stream);

    k_rnn_tf<<<BATCH, 512, 0, stream>>>(y, WHH2, WIH2, CB, Zbuf, ZF);

    // psi: 64-row blocks (halved weight traffic); fall back to the proven
    // 32-row version on any synchronous launch error (e.g. LDS rejection).
    k_psi_bulk64<<<(BATCH * TTF) / 64, 512, 0, stream>>>(
        Zbuf, WB1, WB2, WB3, WB4, WB5, b1, b2, b3, b4, b5, out);
    hipError_t pe = hipGetLastError();
    if (pe != hipSuccess) {
        k_psi_bulk<<<(BATCH * TTF) / 32, 512, 0, stream>>>(
            Zbuf, WB1, WB2, WB3, WB4, WB5, b1, b2, b3, b4, b5, out);
    }

    // Cooperative launch preferred (guaranteed co-residency); on ANY error
    // fall back to a plain launch — 256 blocks at 1+/CU are co-resident.
    void* args[] = {
        (void*)&ZF, (void*)&WB1, (void*)&WB2, (void*)&WB3, (void*)&WB4,
        (void*)&WB5, (void*)&WBC, (void*)&b1, (void*)&b2, (void*)&b3,
        (void*)&b4, (void*)&b5, (void*)&CB, (void*)&HB, (void*)&CTR,
        (void*)&out
    };
    hipError_t ce = hipLaunchCooperativeKernel((const void*)k_ar2,
                                               dim3(ARBLOCKS), dim3(ARTHREADS),
                                               args, 0, stream);
    if (ce != hipSuccess) {
        (void)hipGetLastError();   // clear sticky error
        k_ar2<<<dim3(ARBLOCKS), dim3(ARTHREADS), 0, stream>>>(
            ZF, WB1, WB2, WB3, WB4, WB5, WBC, b1, b2, b3, b4, b5, CB,
            HB, CTR, out);
    }
}

// Round 14
// 6129.151 us; speedup vs baseline: 1.0104x; 1.0078x over previous
//
#include <hip/hip_runtime.h>
#include <stdint.h>

// ---------------------------------------------------------------------------
// RNN rollout. Phase 1: teacher-forced recurrence (scalar, 4-way ILP, R19) +
// bulk psi (64-row blocks, R17). Phase 2: persistent AR kernel, 8 groups x
// 32 members, member m -> XCD m%8 (weight slices L2-resident, R6/R8).
// AR = R14/R19 structure VERBATIM (4745-4760us steady, best known).
// Measured structural floors: AR = 256 serial steps x 4 MALL-RTT hops
// (sync variants R13/R14/R20, hop variants R10/R12/R15, placement R9 all
// measured); psi64 = weight-traffic bound (~3.3GB); rnn_tf = 2-barrier ring
// (ILP R19, K-split R21 null). Failed variants (do not retry): R9 co-located
// groups, R11 in-grid psi fusion, R12 redundant full-L1, R13 epoch flags,
// R15 MALL-atomic L5 reduction, R16 chunked psi GEMMs, R18 MFMA TF
// recurrence, R20 split-publish, R21 K-split rnn_tf.
// R22 change: the 9 prologue prep kernels + their ~100us of serial launch
// overhead fused into ONE grid-stride k_prep (virtual concatenated index
// space, per-element logic verbatim => bitwise-identical buffers).
// Sizes fixed: B=128, T=256, HOR=512, OBS=32, LAT=256, HID=1024.
// ---------------------------------------------------------------------------

#define BATCH 128
#define TTF   256
#define HOR   512
#define OBS   32
#define LAT   256
#define HID   1024

#define GROUPS  8
#define MEMBERS 32
#define ARBLOCKS (GROUPS * MEMBERS)
#define ARTHREADS 128

typedef __attribute__((ext_vector_type(8))) short short8;
typedef __attribute__((ext_vector_type(4))) float floatx4;

// ---- workspace layout (bytes) ----
#define OFF_WB1   ((size_t)0)                          // 1024x256 bf16 ([col][k])
#define OFF_WB2   (OFF_WB1 + (size_t)HID*LAT*2)        // 1024x1024 bf16
#define OFF_WB3   (OFF_WB2 + (size_t)HID*HID*2)
#define OFF_WB4   (OFF_WB3 + (size_t)HID*HID*2)
#define OFF_WB5   (OFF_WB4 + (size_t)HID*HID*2)        // 32x1024 bf16
#define OFF_CB    (OFF_WB5 + (size_t)OBS*HID*2)        // 256 f32 (b_ih+b_hh)
#define OFF_WHH2  (OFF_CB + (size_t)LAT*4)             // 64x256 uint2 packed W_hh^T
#define OFF_WIH2  (OFF_WHH2 + (size_t)64*256*8)        // 8x256 uint2 packed W_ih^T
#define OFF_ZF    (OFF_WIH2 + (size_t)8*256*8)         // 128x256 f32
#define OFF_Z     (OFF_ZF + (size_t)BATCH*LAT*4)       // 32768x256 bf16
#define OFF_WBC   (OFF_Z + (size_t)BATCH*TTF*LAT*2)    // 256x288 bf16 cell matrix
#define OFF_HB    (OFF_WBC + (size_t)LAT*288*2)        // 8 x 2par x 4 x 16x1024 bf16
#define OFF_CTR   (OFF_HB + (size_t)GROUPS*8*16*HID*2) // 8 x 512B counters
#define OFF_END   (OFF_CTR + (size_t)GROUPS*512)

// virtual index-space sizes for the fused prologue
#define NP_WB1  ((size_t)HID*LAT)
#define NP_WBH  ((size_t)HID*HID)
#define NP_WB5  ((size_t)OBS*HID)
#define NP_CB   ((size_t)LAT)
#define NP_WHH2 ((size_t)64*256)
#define NP_WIH2 ((size_t)8*256)
#define NP_WBC  ((size_t)256*288)
#define NP_TOTAL (NP_WB1 + 3*NP_WBH + NP_WB5 + NP_CB + NP_WHH2 + NP_WIH2 + NP_WBC)

__device__ __forceinline__ uint16_t f2bf(float f) {
    uint32_t u = __float_as_uint(f);
    u += 0x7fffu + ((u >> 16) & 1u);   // RNE
    return (uint16_t)(u >> 16);
}
__device__ __forceinline__ float bflo(uint32_t u) { return __uint_as_float(u << 16); }
__device__ __forceinline__ float bfhi(uint32_t u) { return __uint_as_float(u & 0xffff0000u); }

__device__ __forceinline__ float fast_tanh(float x) {
    float ax = fabsf(x);
    float e  = __expf(-2.f * ax);
    float r  = (1.f - e) / (1.f + e);
    return copysignf(r, x);
}

// XOR-granule swizzles (16B granule index ^ low bits of row). Producers store
// swizzled; the verbatim DMA lands swizzled in LDS; readers XOR back.
__device__ __forceinline__ int hswz(int row, int col) {   // h: stride 1024
    return row * 1024 + ((((col >> 3) ^ (row & 7)) << 3) | (col & 7));
}
__device__ __forceinline__ int zswz(int row, int col) {   // z: stride 256
    return row * 256 + ((((col >> 3) ^ (row & 7)) << 3) | (col & 7));
}

// 16B MALL-coherent store (sc0|sc1 write-through, proven R9/R10).
__device__ __forceinline__ void st16_mall(void* p, floatx4 v) {
    asm volatile("global_store_dwordx4 %0, %1, off sc0 sc1"
                 :: "v"(p), "v"(v) : "memory");
}

// async DMA global->LDS, 16 B/lane, aux=0x11 (CPol SC0|SC1): reads at MALL
// (coherent with the sc0|sc1 writers), does not allocate into L1/L2.
typedef const __attribute__((address_space(1))) void* gas_t;
typedef __attribute__((address_space(3))) void* las_t;
__device__ __forceinline__ void gl_lds16(const void* g, void* l) {
    __builtin_amdgcn_global_load_lds((gas_t)g, (las_t)l, 16, 0, 0x11);
}

// 32 KB h tile MALL -> LDS: per wave 16 issues x 1 KB, all in flight.
__device__ __forceinline__ void stage_h(const uint16_t* src, uint16_t* dst,
                                        int w, int L) {
    const char* gp = (const char*)src + w * 16384 + L * 16;
    char* lp = (char*)dst + w * 16384;
    #pragma unroll
    for (int i = 0; i < 16; i++)
        gl_lds16(gp + i * 1024, lp + i * 1024);
}

// ---------------------------------------------------------------------------
// K0 (R22): fused prologue. One grid-stride kernel over a virtual
// concatenation of all prep tasks; per-element logic verbatim from the nine
// original kernels => bitwise-identical buffers.
// ---------------------------------------------------------------------------
__global__ __launch_bounds__(256) void k_prep(
    const float* __restrict__ W1, const float* __restrict__ W2,
    const float* __restrict__ W3, const float* __restrict__ W4,
    const float* __restrict__ W5, const float* __restrict__ b_ih,
    const float* __restrict__ b_hh, const float* __restrict__ W_hh,
    const float* __restrict__ W_ih,
    uint16_t* __restrict__ WB1, uint16_t* __restrict__ WB2,
    uint16_t* __restrict__ WB3, uint16_t* __restrict__ WB4,
    uint16_t* __restrict__ WB5, float* __restrict__ CB,
    uint2* __restrict__ WHH2, uint2* __restrict__ WIH2,
    uint16_t* __restrict__ WBC)
{
    size_t o = (size_t)blockIdx.x * 256 + threadIdx.x;
    if (o < NP_WB1) { WB1[o] = f2bf(W1[o]); return; }
    o -= NP_WB1;
    if (o < NP_WBH) { WB2[o] = f2bf(W2[o]); return; }
    o -= NP_WBH;
    if (o < NP_WBH) { WB3[o] = f2bf(W3[o]); return; }
    o -= NP_WBH;
    if (o < NP_WBH) { WB4[o] = f2bf(W4[o]); return; }
    o -= NP_WBH;
    if (o < NP_WB5) { WB5[o] = f2bf(W5[o]); return; }
    o -= NP_WB5;
    if (o < NP_CB)  { CB[o] = b_ih[o] + b_hh[o]; return; }
    o -= NP_CB;
    if (o < NP_WHH2) {
        int k4 = (int)(o >> 8), j = (int)(o & 255);
        int k = k4 * 4;
        uint32_t a = f2bf(W_hh[(size_t)j * LAT + k + 0]);
        uint32_t b = f2bf(W_hh[(size_t)j * LAT + k + 1]);
        uint32_t c = f2bf(W_hh[(size_t)j * LAT + k + 2]);
        uint32_t d = f2bf(W_hh[(size_t)j * LAT + k + 3]);
        uint2 r; r.x = a | (b << 16); r.y = c | (d << 16);
        WHH2[k4 * 256 + j] = r; return;
    }
    o -= NP_WHH2;
    if (o < NP_WIH2) {
        int k4 = (int)(o >> 8), j = (int)(o & 255);
        int k = k4 * 4;
        uint32_t a = f2bf(W_ih[(size_t)j * OBS + k + 0]);
        uint32_t b = f2bf(W_ih[(size_t)j * OBS + k + 1]);
        uint32_t c = f2bf(W_ih[(size_t)j * OBS + k + 2]);
        uint32_t d = f2bf(W_ih[(size_t)j * OBS + k + 3]);
        uint2 r; r.x = a | (b << 16); r.y = c | (d << 16);
        WIH2[k4 * 256 + j] = r; return;
    }
    o -= NP_WIH2;
    if (o < NP_WBC) {
        int col = (int)(o / 288), k = (int)(o % 288);
        float v = (k < 256) ? W_hh[(size_t)col * 256 + k]
                            : W_ih[(size_t)col * 32 + (k - 256)];
        WBC[(size_t)col * 288 + k] = f2bf(v);
        return;
    }
}

// ---------------------------------------------------------------------------
// K1 (R19): teacher-forced recurrence, scalar with 4-way ILP + y prefetch.
// 128 blocks x 256 threads.
// ---------------------------------------------------------------------------
__global__ __launch_bounds__(256) void k_rnn_tf(
    const float* __restrict__ y, const uint2* __restrict__ whh2,
    const uint2* __restrict__ wih2, const float* __restrict__ cb,
    uint16_t* __restrict__ Zg, float* __restrict__ zfinal)
{
    __shared__ alignas(16) float zl[LAT];
    __shared__ alignas(16) float ys[OBS];
    int j = threadIdx.x, b = blockIdx.x;
    zl[j] = 0.f;
    const float cbj = cb[j];
    float ynext = (j < OBS) ? y[(size_t)b * (TTF * OBS) + j] : 0.f;
    __syncthreads();
    const float4* z4 = (const float4*)zl;
    const float4* y4 = (const float4*)ys;
    for (int t = 0; t < TTF; t++) {
        if (j < OBS) ys[j] = ynext;
        Zg[((size_t)b * TTF + t) * LAT + j] = f2bf(zl[j]);
        __syncthreads();
        // prefetch y[t+1] during the compute (off the critical path)
        if (t + 1 < TTF && j < OBS)
            ynext = y[(size_t)b * (TTF * OBS) + (t + 1) * OBS + j];
        // 4 independent accumulator chains (breaks the 288-FMA dependency)
        float a0 = cbj, a1 = 0.f, a2 = 0.f, a3 = 0.f;
        #pragma unroll 4
        for (int k4 = 0; k4 < 64; k4 += 4) {
            uint2 w0 = whh2[(k4 + 0) * 256 + j]; float4 z0 = z4[k4 + 0];
            uint2 w1 = whh2[(k4 + 1) * 256 + j]; float4 z1 = z4[k4 + 1];
            uint2 w2 = whh2[(k4 + 2) * 256 + j]; float4 z2 = z4[k4 + 2];
            uint2 w3 = whh2[(k4 + 3) * 256 + j]; float4 z3 = z4[k4 + 3];
            a0 += bflo(w0.x) * z0.x + bfhi(w0.x) * z0.y
                + bflo(w0.y) * z0.z + bfhi(w0.y) * z0.w;
            a1 += bflo(w1.x) * z1.x + bfhi(w1.x) * z1.y
                + bflo(w1.y) * z1.z + bfhi(w1.y) * z1.w;
            a2 += bflo(w2.x) * z2.x + bfhi(w2.x) * z2.y
                + bflo(w2.y) * z2.z + bfhi(w2.y) * z2.w;
            a3 += bflo(w3.x) * z3.x + bfhi(w3.x) * z3.y
                + bflo(w3.y) * z3.z + bfhi(w3.y) * z3.w;
        }
        #pragma unroll
        for (int k4 = 0; k4 < 8; k4 += 4) {
            uint2 w0 = wih2[(k4 + 0) * 256 + j]; float4 q0 = y4[k4 + 0];
            uint2 w1 = wih2[(k4 + 1) * 256 + j]; float4 q1 = y4[k4 + 1];
            uint2 w2 = wih2[(k4 + 2) * 256 + j]; float4 q2 = y4[k4 + 2];
            uint2 w3 = wih2[(k4 + 3) * 256 + j]; float4 q3 = y4[k4 + 3];
            a0 += bflo(w0.x) * q0.x + bfhi(w0.x) * q0.y
                + bflo(w0.y) * q0.z + bfhi(w0.y) * q0.w;
            a1 += bflo(w1.x) * q1.x + bfhi(w1.x) * q1.y
                + bflo(w1.y) * q1.z + bfhi(w1.y) * q1.w;
            a2 += bflo(w2.x) * q2.x + bfhi(w2.x) * q2.y
                + bflo(w2.y) * q2.z + bfhi(w2.y) * q2.w;
            a3 += bflo(w3.x) * q3.x + bfhi(w3.x) * q3.y
                + bflo(w3.y) * q3.z + bfhi(w3.y) * q3.w;
        }
        float acc = (a0 + a1) + (a2 + a3);
        __syncthreads();
        zl[j] = fast_tanh(acc);
    }
    __syncthreads();
    zfinal[(size_t)b * LAT + j] = zl[j];
}

// ---------------------------------------------------------------------------
// K2 primary: bulk psi, 64 rows/block (512 blocks, 512 thr, 128KB LDS).
// ---------------------------------------------------------------------------
__global__ __launch_bounds__(512) void k_psi_bulk64(
    const uint16_t* __restrict__ Zg,
    const uint16_t* __restrict__ wb1, const uint16_t* __restrict__ wb2,
    const uint16_t* __restrict__ wb3, const uint16_t* __restrict__ wb4,
    const uint16_t* __restrict__ wb5,
    const float* __restrict__ b1, const float* __restrict__ b2,
    const float* __restrict__ b3, const float* __restrict__ b4,
    const float* __restrict__ b5, float* __restrict__ out)
{
    __shared__ uint16_t hbuf[64 * 1024];   // 128 KB, swizzled
    int tid = threadIdx.x;
    int w = tid >> 6, L = tid & 63, lm = L & 15, q = L >> 4;
    int rb = blockIdx.x * 64;
    int colbase = w * 128;
    floatx4 acc[4][8];
    const floatx4 zero = {0.f, 0.f, 0.f, 0.f};

    #pragma unroll
    for (int rf = 0; rf < 4; rf++)
        #pragma unroll
        for (int nt = 0; nt < 8; nt++) acc[rf][nt] = zero;
    for (int kc = 0; kc < 8; kc++) {
        short8 a[4];
        #pragma unroll
        for (int rf = 0; rf < 4; rf++)
            a[rf] = *(const short8*)(Zg + (size_t)(rb + rf * 16 + lm) * LAT + kc * 32 + q * 8);
        #pragma unroll
        for (int nt = 0; nt < 8; nt++) {
            int n = colbase + nt * 16 + lm;
            short8 bf = *(const short8*)(wb1 + (size_t)n * LAT + kc * 32 + q * 8);
            #pragma unroll
            for (int rf = 0; rf < 4; rf++)
                acc[rf][nt] = __builtin_amdgcn_mfma_f32_16x16x32_bf16(a[rf], bf, acc[rf][nt], 0, 0, 0);
        }
    }
    #pragma unroll
    for (int rf = 0; rf < 4; rf++)
        #pragma unroll
        for (int nt = 0; nt < 8; nt++) {
            int col = colbase + nt * 16 + lm;
            float bias = b1[col];
            #pragma unroll
            for (int i = 0; i < 4; i++) {
                int row = rf * 16 + q * 4 + i;
                hbuf[hswz(row, col)] = f2bf(fmaxf(acc[rf][nt][i] + bias, 0.f));
            }
        }
    __syncthreads();

    const uint16_t* wbs[3] = {wb2, wb3, wb4};
    const float*    bbs[3] = {b2, b3, b4};
    for (int ll = 0; ll < 3; ll++) {
        const uint16_t* wb = wbs[ll];
        const float* bb = bbs[ll];
        #pragma unroll
        for (int rf = 0; rf < 4; rf++)
            #pragma unroll
            for (int nt = 0; nt < 8; nt++) acc[rf][nt] = zero;
        for (int kc = 0; kc < 32; kc++) {
            int g = ((kc * 4 + q) ^ (lm & 7)) << 3;
            short8 a[4];
            #pragma unroll
            for (int rf = 0; rf < 4; rf++)
                a[rf] = *(const short8*)(hbuf + (rf * 16 + lm) * 1024 + g);
            #pragma unroll
            for (int nt = 0; nt < 8; nt++) {
                int n = colbase + nt * 16 + lm;
                short8 bf = *(const short8*)(wb + (size_t)n * HID + kc * 32 + q * 8);
                #pragma unroll
                for (int rf = 0; rf < 4; rf++)
                    acc[rf][nt] = __builtin_amdgcn_mfma_f32_16x16x32_bf16(a[rf], bf, acc[rf][nt], 0, 0, 0);
            }
        }
        __syncthreads();
        #pragma unroll
        for (int rf = 0; rf < 4; rf++)
            #pragma unroll
            for (int nt = 0; nt < 8; nt++) {
                int col = colbase + nt * 16 + lm;
                float bias = bb[col];
                #pragma unroll
                for (int i = 0; i < 4; i++) {
                    int row = rf * 16 + q * 4 + i;
                    hbuf[hswz(row, col)] = f2bf(fmaxf(acc[rf][nt][i] + bias, 0.f));
                }
            }
        __syncthreads();
    }

    // L5: all 8 waves -- wave w = row-frag (w>>1) x col-tile (w&1)
    {
        int rf5 = w >> 1;
        int nb = (w & 1) * 16;
        floatx4 a5 = zero;
        for (int kc = 0; kc < 32; kc++) {
            int g = ((kc * 4 + q) ^ (lm & 7)) << 3;
            short8 a = *(const short8*)(hbuf + (rf5 * 16 + lm) * 1024 + g);
            short8 bf = *(const short8*)(wb5 + (size_t)(nb + lm) * HID + kc * 32 + q * 8);
            a5 = __builtin_amdgcn_mfma_f32_16x16x32_bf16(a, bf, a5, 0, 0, 0);
        }
        int col = nb + lm;
        float bias = b5[col];
        #pragma unroll
        for (int i = 0; i < 4; i++) {
            int r = rb + rf5 * 16 + q * 4 + i;
            int bb_ = r >> 8, tt = r & 255;
            out[(size_t)bb_ * (HOR * OBS) + tt * OBS + col] = a5[i] + bias;
        }
    }
}

// ---------------------------------------------------------------------------
// K2 fallback: bulk psi, 32 rows/block (R10-proven). Launched only if the
// 64-row variant is rejected at launch (synchronous error check).
// ---------------------------------------------------------------------------
__global__ __launch_bounds__(512) void k_psi_bulk(
    const uint16_t* __restrict__ Zg,
    const uint16_t* __restrict__ wb1, const uint16_t* __restrict__ wb2,
    const uint16_t* __restrict__ wb3, const uint16_t* __restrict__ wb4,
    const uint16_t* __restrict__ wb5,
    const float* __restrict__ b1, const float* __restrict__ b2,
    const float* __restrict__ b3, const float* __restrict__ b4,
    const float* __restrict__ b5, float* __restrict__ out)
{
    __shared__ uint16_t hbuf[32 * 1024];   // 64 KB, swizzled
    int tid = threadIdx.x;
    int w = tid >> 6, L = tid & 63, lm = L & 15, q = L >> 4;
    int rb = blockIdx.x * 32;
    int colbase = w * 128;
    floatx4 acc[2][8];
    const floatx4 zero = {0.f, 0.f, 0.f, 0.f};

    #pragma unroll
    for (int mt = 0; mt < 2; mt++)
        #pragma unroll
        for (int nt = 0; nt < 8; nt++) acc[mt][nt] = zero;
    for (int kc = 0; kc < 8; kc++) {
        short8 a0 = *(const short8*)(Zg + (size_t)(rb + lm) * LAT + kc * 32 + q * 8);
        short8 a1 = *(const short8*)(Zg + (size_t)(rb + 16 + lm) * LAT + kc * 32 + q * 8);
        #pragma unroll
        for (int nt = 0; nt < 8; nt++) {
            int n = colbase + nt * 16 + lm;
            short8 bf = *(const short8*)(wb1 + (size_t)n * LAT + kc * 32 + q * 8);
            acc[0][nt] = __builtin_amdgcn_mfma_f32_16x16x32_bf16(a0, bf, acc[0][nt], 0, 0, 0);
            acc[1][nt] = __builtin_amdgcn_mfma_f32_16x16x32_bf16(a1, bf, acc[1][nt], 0, 0, 0);
        }
    }
    #pragma unroll
    for (int mt = 0; mt < 2; mt++)
        #pragma unroll
        for (int nt = 0; nt < 8; nt++) {
            int col = colbase + nt * 16 + lm;
            float bias = b1[col];
            #pragma unroll
            for (int i = 0; i < 4; i++) {
                int row = mt * 16 + q * 4 + i;
                hbuf[hswz(row, col)] = f2bf(fmaxf(acc[mt][nt][i] + bias, 0.f));
            }
        }
    __syncthreads();

    const uint16_t* wbs[3] = {wb2, wb3, wb4};
    const float*    bbs[3] = {b2, b3, b4};
    for (int ll = 0; ll < 3; ll++) {
        const uint16_t* wb = wbs[ll];
        const float* bb = bbs[ll];
        #pragma unroll
        for (int mt = 0; mt < 2; mt++)
            #pragma unroll
            for (int nt = 0; nt < 8; nt++) acc[mt][nt] = zero;
        for (int kc = 0; kc < 32; kc++) {
            int g = ((kc * 4 + q) ^ (lm & 7)) << 3;
            short8 a0 = *(const short8*)(hbuf + lm * 1024 + g);
            short8 a1 = *(const short8*)(hbuf + (16 + lm) * 1024 + g);
            #pragma unroll
            for (int nt = 0; nt < 8; nt++) {
                int n = colbase + nt * 16 + lm;
                short8 bf = *(const short8*)(wb + (size_t)n * HID + kc * 32 + q * 8);
                acc[0][nt] = __builtin_amdgcn_mfma_f32_16x16x32_bf16(a0, bf, acc[0][nt], 0, 0, 0);
                acc[1][nt] = __builtin_amdgcn_mfma_f32_16x16x32_bf16(a1, bf, acc[1][nt], 0, 0, 0);
            }
        }
        __syncthreads();
        #pragma unroll
        for (int mt = 0; mt < 2; mt++)
            #pragma unroll
            for (int nt = 0; nt < 8; nt++) {
                int col = colbase + nt * 16 + lm;
                float bias = bb[col];
                #pragma unroll
                for (int i = 0; i < 4; i++) {
                    int row = mt * 16 + q * 4 + i;
                    hbuf[hswz(row, col)] = f2bf(fmaxf(acc[mt][nt][i] + bias, 0.f));
                }
            }
        __syncthreads();
    }

    if (w < 4) {
        int mt = w >> 1;
        int nb = (w & 1) * 16;
        floatx4 a5 = zero;
        for (int kc = 0; kc < 32; kc++) {
            int g = ((kc * 4 + q) ^ (lm & 7)) << 3;
            short8 a = *(const short8*)(hbuf + (mt * 16 + lm) * 1024 + g);
            short8 bf = *(const short8*)(wb5 + (size_t)(nb + lm) * HID + kc * 32 + q * 8);
            a5 = __builtin_amdgcn_mfma_f32_16x16x32_bf16(a, bf, a5, 0, 0, 0);
        }
        int col = nb + lm;
        float bias = b5[col];
        #pragma unroll
        for (int i = 0; i < 4; i++) {
            int row = mt * 16 + q * 4 + i;
            int r = rb + row;
            int bb_ = r >> 8, tt = r & 255;
            out[(size_t)bb_ * (HOR * OBS) + tt * OBS + col] = a5[i] + bias;
        }
    }
}

// ---------------------------------------------------------------------------
// K3 v14 (R19 verbatim): persistent AR. ARRIVE (wave0 publish + drain +
// lane0 RMW) / overlap (cell z-part CCZ) / WAIT (tid0 spin + 1 barrier).
// Tail: stage h4, L5 redundant, out, cell finish. Step-parity h tiles.
// ---------------------------------------------------------------------------
__global__ __launch_bounds__(ARTHREADS) void k_ar2(
    const float* __restrict__ zfinal,
    const uint16_t* __restrict__ wb1, const uint16_t* __restrict__ wb2,
    const uint16_t* __restrict__ wb3, const uint16_t* __restrict__ wb4,
    const uint16_t* __restrict__ wb5, const uint16_t* __restrict__ wbc,
    const float* __restrict__ b1g, const float* __restrict__ b2g,
    const float* __restrict__ b3g, const float* __restrict__ b4g,
    const float* __restrict__ b5g, const float* __restrict__ cb,
    uint16_t* __restrict__ hb_all, unsigned* __restrict__ ctr_all,
    float* __restrict__ out)
{
    __shared__ alignas(16) uint16_t hstg[16 * 1024];   // 32 KB staged h tile
    __shared__ alignas(16) uint16_t zst[2 * 16 * 256]; // 16 KB z parity buffers
    __shared__ alignas(16) uint16_t yscr[16 * 32];     // 1 KB
    __shared__ alignas(16) uint16_t hsl[16 * 32];      // 1 KB slice transpose

    const int tid = threadIdx.x;
    const int g = blockIdx.x >> 5, m = blockIdx.x & 31;   // member m -> XCD m%8
    const int w = tid >> 6, L = tid & 63, lm = L & 15, q = L >> 4, lm7 = lm & 7;
    const int colbase = m * 32;
    const int cl = w * 16 + lm;
    const int rb = g * 16;
    uint16_t* hb = hb_all + (size_t)g * (8 * 16 * HID);   // 2 parity x 4 slots
    unsigned* ctr = ctr_all + g * 128;
    const floatx4 zero = {0.f, 0.f, 0.f, 0.f};

    // loop-invariant bias loads, hoisted out of the t-loop
    const float b1v = b1g[colbase + cl];
    const float b2v = b2g[colbase + cl];
    const float b3v = b3g[colbase + cl];
    const float b4v = b4g[colbase + cl];
    const float b5v = b5g[cl];
    float cbv[8];
    #pragma unroll
    for (int ct = 0; ct < 8; ct++) cbv[ct] = cb[w * 128 + ct * 16 + lm];

    // initial z: local LDS only (every member keeps its own copy), swizzled
    for (int idx = tid; idx < 16 * 256; idx += ARTHREADS) {
        int r = idx >> 8, c = idx & 255;
        zst[zswz(r, c)] = f2bf(zfinal[(size_t)(rb + r) * LAT + c]);
    }
    __syncthreads();

    // ARRIVE: wave0 publishes slice, drains its stores, lane0 RMWs counter.
    #define HOP_ARRIVE(DST) do {                                             \
        __syncthreads();                                                     \
        if (tid < 64) {                                                      \
            int row_ = tid >> 2, gr_ = tid & 3;                              \
            floatx4 vv_ = *(const floatx4*)((const char*)hsl + tid * 16);    \
            int gsw_ = (m * 4 + gr_) ^ (row_ & 7);                           \
            st16_mall((char*)(DST) + row_ * 2048 + gsw_ * 16, vv_);          \
            asm volatile("s_waitcnt vmcnt(0)" ::: "memory");                 \
            if (tid == 0)                                                    \
                __hip_atomic_fetch_add(ctr, 1u, __ATOMIC_RELAXED,            \
                                       __HIP_MEMORY_SCOPE_AGENT);            \
        }                                                                    \
    } while (0)

    // WAIT: tid0 spins on the group counter, then one block barrier.
    #define HOP_WAIT(TGT) do {                                               \
        if (tid == 0) {                                                      \
            while (__hip_atomic_load(ctr, __ATOMIC_RELAXED,                  \
                                     __HIP_MEMORY_SCOPE_AGENT) < (TGT)) {}   \
        }                                                                    \
        __syncthreads();                                                     \
    } while (0)

    // cell z-part chunk: kc in [K0,K1), accumulated into cc[8]
    #define CCZ(K0, K1) do {                                                 \
        _Pragma("unroll")                                                    \
        for (int ct = 0; ct < 8; ct++) {                                     \
            const uint16_t* bb2_ = wbc + (size_t)(w * 128 + ct * 16 + lm) * 288 + q * 8; \
            _Pragma("unroll")                                                \
            for (int kc = (K0); kc < (K1); kc++) {                           \
                int gz_ = (kc * 4 + q) ^ lm7;                                \
                short8 a_ = *(const short8*)(zcur + lm * 256 + gz_ * 8);     \
                short8 b_ = *(const short8*)(bb2_ + kc * 32);                \
                cc[ct] = __builtin_amdgcn_mfma_f32_16x16x32_bf16(a_, b_, cc[ct], 0, 0, 0); \
            }                                                                \
        }                                                                    \
    } while (0)

    #define MID_COMPUTE(WB, BV) do {                                         \
        floatx4 acc_ = zero;                                                 \
        const uint16_t* bb_ = WB + (size_t)(colbase + cl) * HID + q * 8;     \
        _Pragma("unroll 8")                                                  \
        for (int kc = 0; kc < 32; kc++) {                                    \
            int gh = (kc * 4 + q) ^ lm7;                                     \
            short8 a_ = *(const short8*)(hstg + lm * 1024 + gh * 8);         \
            short8 b_ = *(const short8*)(bb_ + kc * 32);                     \
            acc_ = __builtin_amdgcn_mfma_f32_16x16x32_bf16(a_, b_, acc_, 0, 0, 0); \
        }                                                                    \
        _Pragma("unroll")                                                    \
        for (int i = 0; i < 4; i++)                                          \
            hsl[(q * 4 + i) * 32 + cl] = f2bf(fmaxf(acc_[i] + (BV), 0.f));   \
    } while (0)

    unsigned tgt = 0;
    #pragma unroll 1
    for (int t = 0; t < HOR - TTF; t++) {
        uint16_t* zcur = zst + (t & 1) * (16 * 256);
        uint16_t* znx  = zst + ((t + 1) & 1) * (16 * 256);
        uint16_t* hp = hb + (t & 1) * (4 * 16 * HID);     // step-parity tiles
        uint16_t* h1 = hp;
        uint16_t* h2 = hp + 16 * HID;
        uint16_t* h3 = hp + 2 * 16 * HID;
        uint16_t* h4 = hp + 3 * 16 * HID;

        floatx4 cc[8];
        #pragma unroll
        for (int ct = 0; ct < 8; ct++) cc[ct] = zero;

        // ---- L1 slice from LDS z (local) ----
        {
            floatx4 acc = zero;
            const uint16_t* bb = wb1 + (size_t)(colbase + cl) * LAT + q * 8;
            #pragma unroll
            for (int kc = 0; kc < 8; kc++) {
                int gz = (kc * 4 + q) ^ lm7;
                short8 a = *(const short8*)(zcur + lm * 256 + gz * 8);
                short8 b = *(const short8*)(bb + kc * 32);
                acc = __builtin_amdgcn_mfma_f32_16x16x32_bf16(a, b, acc, 0, 0, 0);
            }
            #pragma unroll
            for (int i = 0; i < 4; i++)
                hsl[(q * 4 + i) * 32 + cl] = f2bf(fmaxf(acc[i] + b1v, 0.f));
        }
        HOP_ARRIVE(h1); tgt += MEMBERS;
        CCZ(0, 2);
        HOP_WAIT(tgt);
        stage_h(h1, hstg, w, L);
        __syncthreads();

        MID_COMPUTE(wb2, b2v);
        HOP_ARRIVE(h2); tgt += MEMBERS;
        CCZ(2, 4);
        HOP_WAIT(tgt);
        stage_h(h2, hstg, w, L);
        __syncthreads();

        MID_COMPUTE(wb3, b3v);
        HOP_ARRIVE(h3); tgt += MEMBERS;
        CCZ(4, 6);
        HOP_WAIT(tgt);
        stage_h(h3, hstg, w, L);
        __syncthreads();

        MID_COMPUTE(wb4, b4v);
        HOP_ARRIVE(h4); tgt += MEMBERS;
        CCZ(6, 8);
        HOP_WAIT(tgt);
        stage_h(h4, hstg, w, L);
        __syncthreads();

        // ---- tail: L5 (redundant), out, cell finish (yh term) ----
        {
            floatx4 a5 = zero;
            const uint16_t* bb = wb5 + (size_t)cl * HID + q * 8;
            #pragma unroll 8
            for (int kc = 0; kc < 32; kc++) {
                int gh = (kc * 4 + q) ^ lm7;
                short8 a = *(const short8*)(hstg + lm * 1024 + gh * 8);
                short8 b = *(const short8*)(bb + kc * 32);
                a5 = __builtin_amdgcn_mfma_f32_16x16x32_bf16(a, b, a5, 0, 0, 0);
            }
            float vout[4];
            #pragma unroll
            for (int i = 0; i < 4; i++) {
                float v = a5[i] + b5v;
                vout[i] = v;
                yscr[(q * 4 + i) * 32 + cl] = f2bf(v);
            }
            if (m == 0) {
                #pragma unroll
                for (int i = 0; i < 4; i++)
                    out[(size_t)(rb + q * 4 + i) * (HOR * OBS) + (TTF + t) * OBS + cl] = vout[i];
            }
        }
        __syncthreads();
        // cell finish: add the yh term (kc=8) to cc[], tanh, write z'
        {
            short8 ay = *(const short8*)(yscr + lm * 32 + q * 8);
            #pragma unroll
            for (int ct = 0; ct < 8; ct++) {
                int ccol = w * 128 + ct * 16 + lm;
                const uint16_t* bb2 = wbc + (size_t)ccol * 288 + q * 8;
                short8 b = *(const short8*)(bb2 + 8 * 32);
                floatx4 v = __builtin_amdgcn_mfma_f32_16x16x32_bf16(ay, b, cc[ct], 0, 0, 0);
                #pragma unroll
                for (int i = 0; i < 4; i++)
                    znx[zswz(q * 4 + i, ccol)] = f2bf(fast_tanh(v[i] + cbv[ct]));
            }
        }
        __syncthreads();
    }
    #undef MID_COMPUTE
    #undef CCZ
    #undef HOP_WAIT
    #undef HOP_ARRIVE
}

// ---------------------------------------------------------------------------
extern "C" void kernel_launch(void* const* d_in, const int* in_sizes, int n_in,
                              void* d_out, int out_size, void* d_ws, size_t ws_size,
                              hipStream_t stream) {
    (void)in_sizes; (void)n_in; (void)out_size; (void)ws_size;
    const float* y    = (const float*)d_in[0];
    const float* W_ih = (const float*)d_in[2];
    const float* W_hh = (const float*)d_in[3];
    const float* b_ih = (const float*)d_in[4];
    const float* b_hh = (const float*)d_in[5];
    const float* W1   = (const float*)d_in[6];
    const float* b1   = (const float*)d_in[7];
    const float* W2   = (const float*)d_in[8];
    const float* b2   = (const float*)d_in[9];
    const float* W3   = (const float*)d_in[10];
    const float* b3   = (const float*)d_in[11];
    const float* W4   = (const float*)d_in[12];
    const float* b4   = (const float*)d_in[13];
    const float* W5   = (const float*)d_in[14];
    const float* b5   = (const float*)d_in[15];
    float* out = (float*)d_out;
    char* ws = (char*)d_ws;

    uint16_t* WB1  = (uint16_t*)(ws + OFF_WB1);
    uint16_t* WB2  = (uint16_t*)(ws + OFF_WB2);
    uint16_t* WB3  = (uint16_t*)(ws + OFF_WB3);
    uint16_t* WB4  = (uint16_t*)(ws + OFF_WB4);
    uint16_t* WB5  = (uint16_t*)(ws + OFF_WB5);
    float*    CB   = (float*)(ws + OFF_CB);
    uint2*    WHH2 = (uint2*)(ws + OFF_WHH2);
    uint2*    WIH2 = (uint2*)(ws + OFF_WIH2);
    float*    ZF   = (float*)(ws + OFF_ZF);
    uint16_t* Zbuf = (uint16_t*)(ws + OFF_Z);
    uint16_t* WBC  = (uint16_t*)(ws + OFF_WBC);
    uint16_t* HB   = (uint16_t*)(ws + OFF_HB);
    unsigned* CTR  = (unsigned*)(ws + OFF_CTR);

    // fused prologue: one launch covers all conversions/packs (R22)
    {
        int nblk = (int)((NP_TOTAL + 255) / 256);
        k_prep<<<nblk, 256, 0, stream>>>(
            W1, W2, W3, W4, W5, b_ih, b_hh, W_hh, W_ih,
            WB1, WB2, WB3, WB4, WB5, CB, WHH2, WIH2, WBC);
    }
    hipMemsetAsync(CTR, 0, GROUPS * 512, stream);

    k_rnn_tf<<<BATCH, 256, 0, stream>>>(y, WHH2, WIH2, CB, Zbuf, ZF);

    // psi: 64-row blocks (halved weight traffic); fall back to the proven
    // 32-row version on any synchronous launch error (e.g. LDS rejection).
    k_psi_bulk64<<<(BATCH * TTF) / 64, 512, 0, stream>>>(
        Zbuf, WB1, WB2, WB3, WB4, WB5, b1, b2, b3, b4, b5, out);
    hipError_t pe = hipGetLastError();
    if (pe != hipSuccess) {
        k_psi_bulk<<<(BATCH * TTF) / 32, 512, 0, stream>>>(
            Zbuf, WB1, WB2, WB3, WB4, WB5, b1, b2, b3, b4, b5, out);
    }

    // Cooperative launch preferred (guaranteed co-residency); on ANY error
    // fall back to a plain launch — 256 blocks at 1+/CU are co-resident.
    void* args[] = {
        (void*)&ZF, (void*)&WB1, (void*)&WB2, (void*)&WB3, (void*)&WB4,
        (void*)&WB5, (void*)&WBC, (void*)&b1, (void*)&b2, (void*)&b3,
        (void*)&b4, (void*)&b5, (void*)&CB, (void*)&HB, (void*)&CTR,
        (void*)&out
    };
    hipError_t ce = hipLaunchCooperativeKernel((const void*)k_ar2,
                                               dim3(ARBLOCKS), dim3(ARTHREADS),
                                               args, 0, stream);
    if (ce != hipSuccess) {
        (void)hipGetLastError();   // clear sticky error
        k_ar2<<<dim3(ARBLOCKS), dim3(ARTHREADS), 0, stream>>>(
            ZF, WB1, WB2, WB3, WB4, WB5, WBC, b1, b2, b3, b4, b5, CB,
            HB, CTR, out);
    }
}